// Round 1
// baseline (7331.981 us; speedup 1.0000x reference)
//
#include <hip/hip_runtime.h>
#include <hip/hip_bf16.h>

#define DIM   4096
#define NH    32
#define NKV   8
#define HD    128
#define FFNH  11008
#define BATCH 4
#define SEQ   2048
#define MTOT  (BATCH*SEQ)   // 8192

using bf16x8_t = __attribute__((ext_vector_type(8))) short;
using f32x4_t  = __attribute__((ext_vector_type(4))) float;

typedef const __attribute__((address_space(1))) unsigned int GlbU32;
typedef __attribute__((address_space(3))) unsigned int LdsU32;

__device__ __forceinline__ unsigned short f2b(float f) {
  union { float f; unsigned int u; } v; v.f = f;
  return (unsigned short)((v.u + 0x7fffu + ((v.u >> 16) & 1u)) >> 16);
}
__device__ __forceinline__ float b2f(unsigned short b) {
  union { unsigned int u; float f; } v; v.u = ((unsigned int)b) << 16;
  return v.f;
}
__device__ __forceinline__ void gll16(const void* g, void* l) {
  __builtin_amdgcn_global_load_lds((GlbU32*)g, (LdsU32*)l, 16, 0, 0);
}

// ---------------- RMSNorm: fp32 in -> bf16 out ----------------
__global__ __launch_bounds__(256)
void rmsnorm_k(const float* __restrict__ X, const float* __restrict__ gamma,
               unsigned short* __restrict__ Y)
{
  const int row = blockIdx.x, t = threadIdx.x;
  const float* xr = X + (size_t)row * DIM;
  float4 v[4];
  float ss = 0.f;
#pragma unroll
  for (int p = 0; p < 4; ++p) {
    v[p] = *(const float4*)&xr[p * 1024 + t * 4];
    ss += v[p].x*v[p].x + v[p].y*v[p].y + v[p].z*v[p].z + v[p].w*v[p].w;
  }
#pragma unroll
  for (int off = 32; off >= 1; off >>= 1) ss += __shfl_xor(ss, off, 64);
  __shared__ float red[4];
  if ((t & 63) == 0) red[t >> 6] = ss;
  __syncthreads();
  const float tot = red[0] + red[1] + red[2] + red[3];
  const float rn = rsqrtf(tot * (1.f / DIM) + 1e-6f);
  unsigned short* yr = Y + (size_t)row * DIM;
#pragma unroll
  for (int p = 0; p < 4; ++p) {
    const float4 gv = *(const float4*)&gamma[p * 1024 + t * 4];
    short4 o;
    o.x = (short)f2b(v[p].x * gv.x * rn);
    o.y = (short)f2b(v[p].y * gv.y * rn);
    o.z = (short)f2b(v[p].z * gv.z * rn);
    o.w = (short)f2b(v[p].w * gv.w * rn);
    *(short4*)&yr[p * 1024 + t * 4] = o;
  }
}

// ---------------- RoPE in-place on bf16 [rows][NHT*128] ----------------
template<int NHT>
__global__ __launch_bounds__(256)
void rope_k(unsigned short* __restrict__ buf, const float* __restrict__ fr)
{
  const int u = blockIdx.x * 256 + threadIdx.x;    // one thread = 4 pairs
  const int per_row = NHT * 16;
  const int row  = u / per_row;
  const int rem  = u - row * per_row;
  const int head = rem >> 4;
  const int i4   = (rem & 15) << 2;                // pair index base
  const int s    = row & (SEQ - 1);
  unsigned short* p = buf + (size_t)row * (NHT * HD) + head * HD + i4 * 2;
  union { int4 v; unsigned short u16[8]; } d;
  d.v = *(const int4*)p;
  const float4 f = *(const float4*)&fr[s * 64 + i4];
  const float fa[4] = {f.x, f.y, f.z, f.w};
#pragma unroll
  for (int i = 0; i < 4; ++i) {
    float sn, c;
    __sincosf(fa[i], &sn, &c);
    const float x0 = b2f(d.u16[2*i]), x1 = b2f(d.u16[2*i+1]);
    d.u16[2*i]   = f2b(x0 * c - x1 * sn);
    d.u16[2*i+1] = f2b(x0 * sn + x1 * c);
  }
  *(int4*)p = d.v;
}

// ---------------- GEMM: C[M,N] = A[M,K](bf16) * W[N,K]^T(fp32->bf16) ----------------
// EPI 0: +bias -> bf16 out.  EPI 1: +bias +res(f32) -> f32 out.  EPI 2: +res(f32) -> f32 out.
template<int EPI>
__global__ __launch_bounds__(256)
void gemm_bt(const unsigned short* __restrict__ A, const float* __restrict__ W,
             const float* __restrict__ bias, const float* __restrict__ res,
             void* __restrict__ Cout, int M, int N, int K)
{
  __shared__ unsigned short As[2][4096];   // 128 x 32
  __shared__ unsigned short Bs[2][4096];   // 128 x 32
  const int t = threadIdx.x;
  const int lane = t & 63, wid = t >> 6;
  const int wr = wid >> 1, wc = wid & 1;
  const int nbn = N >> 7;
  const int tm = blockIdx.x / nbn, tn = blockIdx.x % nbn;
  const int m0 = tm << 7, n0 = tn << 7;
  const int nk = K >> 5;

  const int brow = t >> 3;                 // + 32*s
  const int bcol = (t & 7) << 2;
  const int arow0 = lane >> 2;             // + o*16
  const int acol  = (lane & 3) << 3;

  float4 breg[4];

  auto loadB = [&](int ks) {
#pragma unroll
    for (int s2 = 0; s2 < 4; ++s2) {
      const int row = brow + (s2 << 5);
      breg[s2] = *(const float4*)&W[(size_t)(n0 + row) * K + (ks << 5) + bcol];
    }
  };
  auto writeB = [&](int buf) {
#pragma unroll
    for (int s2 = 0; s2 < 4; ++s2) {
      short4 pk;
      pk.x = (short)f2b(breg[s2].x); pk.y = (short)f2b(breg[s2].y);
      pk.z = (short)f2b(breg[s2].z); pk.w = (short)f2b(breg[s2].w);
      *(short4*)&Bs[buf][t * 4 + s2 * 1024] = pk;
    }
  };
  auto stageA = [&](int buf, int ks) {
#pragma unroll
    for (int oo = 0; oo < 2; ++oo) {
      const int o = wid * 2 + oo;
      const unsigned short* gp = A + (size_t)(m0 + o * 16 + arow0) * K + (ks << 5) + acol;
      gll16(gp, &As[buf][o * 512]);
    }
  };

  f32x4_t acc[4][4];
#pragma unroll
  for (int i = 0; i < 4; ++i)
#pragma unroll
    for (int j = 0; j < 4; ++j) acc[i][j] = (f32x4_t)0.f;

  loadB(0); writeB(0); stageA(0, 0);

  for (int kt = 0; kt < nk; ++kt) {
    __syncthreads();
    const int cur = kt & 1;
    const bool more = (kt + 1 < nk);
    if (more) loadB(kt + 1);              // issue next-tile global loads early
    bf16x8_t af[4], bf[4];
#pragma unroll
    for (int mi = 0; mi < 4; ++mi)
      af[mi] = *(const bf16x8_t*)&As[cur][(wr * 64 + mi * 16 + (lane & 15)) * 32 + (lane >> 4) * 8];
#pragma unroll
    for (int ni = 0; ni < 4; ++ni)
      bf[ni] = *(const bf16x8_t*)&Bs[cur][(wc * 64 + ni * 16 + (lane & 15)) * 32 + (lane >> 4) * 8];
#pragma unroll
    for (int mi = 0; mi < 4; ++mi)
#pragma unroll
      for (int ni = 0; ni < 4; ++ni)
        acc[mi][ni] = __builtin_amdgcn_mfma_f32_16x16x32_bf16(af[mi], bf[ni], acc[mi][ni], 0, 0, 0);
    if (more) { writeB(cur ^ 1); stageA(cur ^ 1, kt + 1); }
  }

#pragma unroll
  for (int ni = 0; ni < 4; ++ni) {
    const int col = n0 + wc * 64 + ni * 16 + (lane & 15);
    float bv = 0.f;
    if constexpr (EPI != 2) bv = bias[col];
#pragma unroll
    for (int mi = 0; mi < 4; ++mi) {
#pragma unroll
      for (int r = 0; r < 4; ++r) {
        const int row = m0 + wr * 64 + mi * 16 + (lane >> 4) * 4 + r;
        const float vv = acc[mi][ni][r] + bv;
        if constexpr (EPI == 0) {
          ((unsigned short*)Cout)[(size_t)row * N + col] = f2b(vv);
        } else if constexpr (EPI == 1) {
          ((float*)Cout)[(size_t)row * N + col] = vv + res[(size_t)row * N + col];
        } else {
          ((float*)Cout)[(size_t)row * N + col] = vv + res[(size_t)row * N + col];
        }
      }
    }
  }
}

// ---------------- fused W1/W3 + SwiGLU: G = silu(A*W1^T) * (A*W3^T) -> bf16 ----------------
__global__ __launch_bounds__(256)
void gemm_w13(const unsigned short* __restrict__ A, const float* __restrict__ W1,
              const float* __restrict__ W3, unsigned short* __restrict__ G)
{
  __shared__ unsigned short As[2][4096];   // 128 x 32
  __shared__ unsigned short B1s[2][2048];  // 64 x 32
  __shared__ unsigned short B3s[2][2048];
  const int t = threadIdx.x;
  const int lane = t & 63, wid = t >> 6;
  const int wr = wid >> 1, wc = wid & 1;
  const int nbn = FFNH / 64;               // 172
  const int tm = blockIdx.x / nbn, tn = blockIdx.x % nbn;
  const int m0 = tm << 7, n0 = tn << 6;
  const int K = DIM, nk = K >> 5;

  const int brow = t >> 3;                 // + 32*s
  const int bcol = (t & 7) << 2;
  const int arow0 = lane >> 2;
  const int acol  = (lane & 3) << 3;

  float4 b1reg[2], b3reg[2];

  auto loadB = [&](int ks) {
#pragma unroll
    for (int s2 = 0; s2 < 2; ++s2) {
      const int row = brow + (s2 << 5);
      b1reg[s2] = *(const float4*)&W1[(size_t)(n0 + row) * K + (ks << 5) + bcol];
      b3reg[s2] = *(const float4*)&W3[(size_t)(n0 + row) * K + (ks << 5) + bcol];
    }
  };
  auto writeB = [&](int buf) {
#pragma unroll
    for (int s2 = 0; s2 < 2; ++s2) {
      short4 p1, p3;
      p1.x = (short)f2b(b1reg[s2].x); p1.y = (short)f2b(b1reg[s2].y);
      p1.z = (short)f2b(b1reg[s2].z); p1.w = (short)f2b(b1reg[s2].w);
      p3.x = (short)f2b(b3reg[s2].x); p3.y = (short)f2b(b3reg[s2].y);
      p3.z = (short)f2b(b3reg[s2].z); p3.w = (short)f2b(b3reg[s2].w);
      *(short4*)&B1s[buf][t * 4 + s2 * 1024] = p1;
      *(short4*)&B3s[buf][t * 4 + s2 * 1024] = p3;
    }
  };
  auto stageA = [&](int buf, int ks) {
#pragma unroll
    for (int oo = 0; oo < 2; ++oo) {
      const int o = wid * 2 + oo;
      const unsigned short* gp = A + (size_t)(m0 + o * 16 + arow0) * K + (ks << 5) + acol;
      gll16(gp, &As[buf][o * 512]);
    }
  };

  f32x4_t acc1[4][2], acc3[4][2];
#pragma unroll
  for (int i = 0; i < 4; ++i)
#pragma unroll
    for (int j = 0; j < 2; ++j) { acc1[i][j] = (f32x4_t)0.f; acc3[i][j] = (f32x4_t)0.f; }

  loadB(0); writeB(0); stageA(0, 0);

  for (int kt = 0; kt < nk; ++kt) {
    __syncthreads();
    const int cur = kt & 1;
    const bool more = (kt + 1 < nk);
    if (more) loadB(kt + 1);
    bf16x8_t af[4], b1f[2], b3f[2];
#pragma unroll
    for (int mi = 0; mi < 4; ++mi)
      af[mi] = *(const bf16x8_t*)&As[cur][(wr * 64 + mi * 16 + (lane & 15)) * 32 + (lane >> 4) * 8];
#pragma unroll
    for (int ni = 0; ni < 2; ++ni) {
      b1f[ni] = *(const bf16x8_t*)&B1s[cur][(wc * 32 + ni * 16 + (lane & 15)) * 32 + (lane >> 4) * 8];
      b3f[ni] = *(const bf16x8_t*)&B3s[cur][(wc * 32 + ni * 16 + (lane & 15)) * 32 + (lane >> 4) * 8];
    }
#pragma unroll
    for (int mi = 0; mi < 4; ++mi)
#pragma unroll
      for (int ni = 0; ni < 2; ++ni) {
        acc1[mi][ni] = __builtin_amdgcn_mfma_f32_16x16x32_bf16(af[mi], b1f[ni], acc1[mi][ni], 0, 0, 0);
        acc3[mi][ni] = __builtin_amdgcn_mfma_f32_16x16x32_bf16(af[mi], b3f[ni], acc3[mi][ni], 0, 0, 0);
      }
    if (more) { writeB(cur ^ 1); stageA(cur ^ 1, kt + 1); }
  }

#pragma unroll
  for (int ni = 0; ni < 2; ++ni) {
    const int col = n0 + wc * 32 + ni * 16 + (lane & 15);
#pragma unroll
    for (int mi = 0; mi < 4; ++mi) {
#pragma unroll
      for (int r = 0; r < 4; ++r) {
        const int row = m0 + wr * 64 + mi * 16 + (lane >> 4) * 4 + r;
        const float s1 = acc1[mi][ni][r];
        const float s3 = acc3[mi][ni][r];
        const float sig = 1.f / (1.f + __expf(-s1));
        G[(size_t)row * FFNH + col] = f2b(s1 * sig * s3);
      }
    }
  }
}

// ---------------- Flash attention (non-causal, GQA 4:1) ----------------
// block: (b, h, 64 q rows); 4 waves x 16 rows; KV tiles of 32.
__global__ __launch_bounds__(256)
void attn_k(const unsigned short* __restrict__ Q, const unsigned short* __restrict__ Kb,
            const unsigned short* __restrict__ Vb, unsigned short* __restrict__ O)
{
  __shared__ unsigned short Qs[8192];   // 64 x 128, XOR-swizzled
  __shared__ unsigned short Ks[4096];   // 32 x 128, XOR-swizzled
  __shared__ unsigned short Vt[4096];   // 128 x 32 (V^T), XOR-swizzled cols
  __shared__ unsigned short Ps[2048];   // per-wave 16 x 32
  const int t = threadIdx.x, lane = t & 63, wid = t >> 6;
  const int bx = blockIdx.x;
  const int qt = bx & 31, h = (bx >> 5) & 31, b = bx >> 10;
  const int kvh = h >> 2;
  const float rs = 0.08838834764831845f;   // 1/sqrt(128)

  // stage Q once (pre-swizzled global source -> linear LDS dest)
#pragma unroll
  for (int oo = 0; oo < 4; ++oo) {
    const int o = wid * 4 + oo;
    const int row = o * 4 + (lane >> 4);            // 0..63
    const int gl  = (lane & 15) ^ (row & 7);
    const unsigned short* gp = Q + (size_t)(b * SEQ + qt * 64 + row) * DIM + h * HD + gl * 8;
    gll16(gp, &Qs[o * 512]);
  }

  f32x4_t oa[8];
#pragma unroll
  for (int i = 0; i < 8; ++i) oa[i] = (f32x4_t)0.f;
  float mrun[4] = {-1e30f, -1e30f, -1e30f, -1e30f};
  float lrun[4] = {0.f, 0.f, 0.f, 0.f};
  const int q0 = wid * 16;

  for (int kt = 0; kt < SEQ / 32; ++kt) {
    // stage K tile
#pragma unroll
    for (int oo = 0; oo < 2; ++oo) {
      const int o = wid * 2 + oo;
      const int row = o * 4 + (lane >> 4);          // 0..31
      const int gl  = (lane & 15) ^ (row & 7);
      const unsigned short* gp = Kb + (size_t)(b * SEQ + kt * 32 + row) * (NKV * HD) + kvh * HD + gl * 8;
      gll16(gp, &Ks[o * 512]);
    }
    // stage V transposed (reg-staged)
    {
      const int kv = t >> 3;
      const int dc = (t & 7) << 4;
      const unsigned short* gp = Vb + (size_t)(b * SEQ + kt * 32 + kv) * (NKV * HD) + kvh * HD + dc;
      union { int4 v; unsigned short u[8]; } lo, hi;
      lo.v = *(const int4*)gp;
      hi.v = *(const int4*)(gp + 8);
      const int colv = kv ^ ((t & 3) << 3);
#pragma unroll
      for (int j = 0; j < 8; ++j) Vt[(dc + j) * 32 + colv] = lo.u[j];
#pragma unroll
      for (int j = 0; j < 8; ++j) Vt[(dc + 8 + j) * 32 + colv] = hi.u[j];
    }
    __syncthreads();

    // S = Q K^T
    f32x4_t sa[2];
    sa[0] = (f32x4_t)0.f; sa[1] = (f32x4_t)0.f;
    const int arow = q0 + (lane & 15);
#pragma unroll
    for (int ks = 0; ks < 4; ++ks) {
      const bf16x8_t aq = *(const bf16x8_t*)&Qs[(arow * 128 + ks * 32 + (lane >> 4) * 8) ^ ((arow & 7) << 3)];
#pragma unroll
      for (int nt = 0; nt < 2; ++nt) {
        const int krow = nt * 16 + (lane & 15);
        const bf16x8_t bk = *(const bf16x8_t*)&Ks[(krow * 128 + ks * 32 + (lane >> 4) * 8) ^ ((krow & 7) << 3)];
        sa[nt] = __builtin_amdgcn_mfma_f32_16x16x32_bf16(aq, bk, sa[nt], 0, 0, 0);
      }
    }
    // online softmax (rows (lane>>4)*4+r, cols across 16-lane groups)
    float pm[4];
#pragma unroll
    for (int r = 0; r < 4; ++r) {
      float v = fmaxf(sa[0][r], sa[1][r]) * rs;
#pragma unroll
      for (int off = 1; off < 16; off <<= 1) v = fmaxf(v, __shfl_xor(v, off, 64));
      pm[r] = v;
    }
    float corr[4], mnew[4];
#pragma unroll
    for (int r = 0; r < 4; ++r) {
      mnew[r] = fmaxf(mrun[r], pm[r]);
      corr[r] = __expf(mrun[r] - mnew[r]);
      mrun[r] = mnew[r];
    }
    float pv[2][4];
#pragma unroll
    for (int nt = 0; nt < 2; ++nt)
#pragma unroll
      for (int r = 0; r < 4; ++r)
        pv[nt][r] = __expf(sa[nt][r] * rs - mnew[r]);
#pragma unroll
    for (int r = 0; r < 4; ++r) {
      float v = pv[0][r] + pv[1][r];
#pragma unroll
      for (int off = 1; off < 16; off <<= 1) v += __shfl_xor(v, off, 64);
      lrun[r] = lrun[r] * corr[r] + v;
    }
#pragma unroll
    for (int i = 0; i < 8; ++i)
#pragma unroll
      for (int r = 0; r < 4; ++r) oa[i][r] *= corr[r];

    // P: C-layout -> LDS -> A-layout (per-wave region, in-wave ordering)
#pragma unroll
    for (int nt = 0; nt < 2; ++nt)
#pragma unroll
      for (int r = 0; r < 4; ++r)
        Ps[wid * 512 + ((lane >> 4) * 4 + r) * 32 + nt * 16 + (lane & 15)] = f2b(pv[nt][r]);
    const bf16x8_t pf = *(const bf16x8_t*)&Ps[wid * 512 + (lane & 15) * 32 + (lane >> 4) * 8];

    // O += P V
#pragma unroll
    for (int nt2 = 0; nt2 < 8; ++nt2) {
      const bf16x8_t vf = *(const bf16x8_t*)&Vt[(nt2 * 16 + (lane & 15)) * 32 + (((lane >> 4) ^ (nt2 & 3)) << 3)];
      oa[nt2] = __builtin_amdgcn_mfma_f32_16x16x32_bf16(pf, vf, oa[nt2], 0, 0, 0);
    }
    __syncthreads();
  }

  float inv[4];
#pragma unroll
  for (int r = 0; r < 4; ++r) inv[r] = 1.f / lrun[r];
#pragma unroll
  for (int nt2 = 0; nt2 < 8; ++nt2) {
    const int col = h * HD + nt2 * 16 + (lane & 15);
#pragma unroll
    for (int r = 0; r < 4; ++r) {
      const int row = qt * 64 + q0 + (lane >> 4) * 4 + r;
      O[(size_t)(b * SEQ + row) * DIM + col] = f2b(oa[nt2][r] * inv[r]);
    }
  }
}

// ---------------- launch ----------------
extern "C" void kernel_launch(void* const* d_in, const int* in_sizes, int n_in,
                              void* d_out, int out_size, void* d_ws, size_t ws_size,
                              hipStream_t stream)
{
  (void)in_sizes; (void)n_in; (void)out_size; (void)ws_size;
  const float* x   = (const float*)d_in[0];
  const float* fr  = (const float*)d_in[1];
  const float* ga  = (const float*)d_in[3];
  const float* gf  = (const float*)d_in[4];
  const float* wq  = (const float*)d_in[5];
  const float* wqb = (const float*)d_in[6];
  const float* wk  = (const float*)d_in[7];
  const float* wkb = (const float*)d_in[8];
  const float* wv  = (const float*)d_in[9];
  const float* wvb = (const float*)d_in[10];
  const float* wo  = (const float*)d_in[11];
  const float* wob = (const float*)d_in[12];
  const float* w1  = (const float*)d_in[13];
  const float* w3  = (const float*)d_in[14];
  const float* w2  = (const float*)d_in[15];
  float* out = (float*)d_out;

  char* ws = (char*)d_ws;
  unsigned short* xn = (unsigned short*)(ws);                  // 64 MiB
  unsigned short* qb = (unsigned short*)(ws + 67108864ull);    // 64 MiB
  unsigned short* kb = (unsigned short*)(ws + 134217728ull);   // 16 MiB
  unsigned short* vb = (unsigned short*)(ws + 150994944ull);   // 16 MiB
  unsigned short* ao = (unsigned short*)(ws + 167772160ull);   // 64 MiB
  unsigned short* hn = (unsigned short*)(ws + 234881024ull);   // 64 MiB
  unsigned short* g  = (unsigned short*)(ws);                  // 172 MiB, aliases xn..ao (dead by then)

  rmsnorm_k<<<MTOT, 256, 0, stream>>>(x, ga, xn);
  gemm_bt<0><<<(MTOT/128)*(DIM/128),   256, 0, stream>>>(xn, wq, wqb, nullptr, qb, MTOT, DIM,     DIM);
  gemm_bt<0><<<(MTOT/128)*(NKV*HD/128),256, 0, stream>>>(xn, wk, wkb, nullptr, kb, MTOT, NKV*HD,  DIM);
  gemm_bt<0><<<(MTOT/128)*(NKV*HD/128),256, 0, stream>>>(xn, wv, wvb, nullptr, vb, MTOT, NKV*HD,  DIM);
  rope_k<NH><<<(MTOT*NH*16)/256,  256, 0, stream>>>(qb, fr);
  rope_k<NKV><<<(MTOT*NKV*16)/256,256, 0, stream>>>(kb, fr);
  attn_k<<<BATCH*NH*(SEQ/64), 256, 0, stream>>>(qb, kb, vb, ao);
  gemm_bt<1><<<(MTOT/128)*(DIM/128), 256, 0, stream>>>(ao, wo, wob, x, out, MTOT, DIM, DIM);
  rmsnorm_k<<<MTOT, 256, 0, stream>>>(out, gf, hn);
  gemm_w13<<<(MTOT/128)*(FFNH/64), 256, 0, stream>>>(hn, w1, w3, g);
  gemm_bt<2><<<(MTOT/128)*(DIM/128), 256, 0, stream>>>(g, w2, nullptr, out, out, MTOT, DIM, FFNH);
}

// Round 2
// 5195.618 us; speedup vs baseline: 1.4112x; 1.4112x over previous
//
#include <hip/hip_runtime.h>
#include <hip/hip_bf16.h>

#define DIM   4096
#define NH    32
#define NKV   8
#define HD    128
#define FFNH  11008
#define BATCH 4
#define SEQ   2048
#define MTOT  (BATCH*SEQ)   // 8192

using bf16x8_t = __attribute__((ext_vector_type(8))) short;
using f32x4_t  = __attribute__((ext_vector_type(4))) float;

typedef const __attribute__((address_space(1))) unsigned int GlbU32;
typedef __attribute__((address_space(3))) unsigned int LdsU32;

__device__ __forceinline__ unsigned short f2b(float f) {
  union { float f; unsigned int u; } v; v.f = f;
  return (unsigned short)((v.u + 0x7fffu + ((v.u >> 16) & 1u)) >> 16);
}
__device__ __forceinline__ float b2f(unsigned short b) {
  union { unsigned int u; float f; } v; v.u = ((unsigned int)b) << 16;
  return v.f;
}
__device__ __forceinline__ void gll16(const void* g, void* l) {
  __builtin_amdgcn_global_load_lds((GlbU32*)g, (LdsU32*)l, 16, 0, 0);
}

// ---------------- fp32 -> bf16 bulk convert (8 elems/thread) ----------------
__global__ __launch_bounds__(256)
void cvt_bf16_k(const float* __restrict__ src, unsigned short* __restrict__ dst)
{
  const size_t i = ((size_t)blockIdx.x * 256 + threadIdx.x) * 8;
  const float4 a = *(const float4*)&src[i];
  const float4 b = *(const float4*)&src[i + 4];
  union { int4 v; unsigned short u[8]; } o;
  o.u[0] = f2b(a.x); o.u[1] = f2b(a.y); o.u[2] = f2b(a.z); o.u[3] = f2b(a.w);
  o.u[4] = f2b(b.x); o.u[5] = f2b(b.y); o.u[6] = f2b(b.z); o.u[7] = f2b(b.w);
  *(int4*)&dst[i] = o.v;
}

// ---------------- RMSNorm: fp32 in -> bf16 out ----------------
__global__ __launch_bounds__(256)
void rmsnorm_k(const float* __restrict__ X, const float* __restrict__ gamma,
               unsigned short* __restrict__ Y)
{
  const int row = blockIdx.x, t = threadIdx.x;
  const float* xr = X + (size_t)row * DIM;
  float4 v[4];
  float ss = 0.f;
#pragma unroll
  for (int p = 0; p < 4; ++p) {
    v[p] = *(const float4*)&xr[p * 1024 + t * 4];
    ss += v[p].x*v[p].x + v[p].y*v[p].y + v[p].z*v[p].z + v[p].w*v[p].w;
  }
#pragma unroll
  for (int off = 32; off >= 1; off >>= 1) ss += __shfl_xor(ss, off, 64);
  __shared__ float red[4];
  if ((t & 63) == 0) red[t >> 6] = ss;
  __syncthreads();
  const float tot = red[0] + red[1] + red[2] + red[3];
  const float rn = rsqrtf(tot * (1.f / DIM) + 1e-6f);
  unsigned short* yr = Y + (size_t)row * DIM;
#pragma unroll
  for (int p = 0; p < 4; ++p) {
    const float4 gv = *(const float4*)&gamma[p * 1024 + t * 4];
    short4 o;
    o.x = (short)f2b(v[p].x * gv.x * rn);
    o.y = (short)f2b(v[p].y * gv.y * rn);
    o.z = (short)f2b(v[p].z * gv.z * rn);
    o.w = (short)f2b(v[p].w * gv.w * rn);
    *(short4*)&yr[p * 1024 + t * 4] = o;
  }
}

// ---------------- RoPE in-place on bf16 [rows][NHT*128] ----------------
template<int NHT>
__global__ __launch_bounds__(256)
void rope_k(unsigned short* __restrict__ buf, const float* __restrict__ fr)
{
  const int u = blockIdx.x * 256 + threadIdx.x;    // one thread = 4 pairs
  const int per_row = NHT * 16;
  const int row  = u / per_row;
  const int rem  = u - row * per_row;
  const int head = rem >> 4;
  const int i4   = (rem & 15) << 2;                // pair index base
  const int s    = row & (SEQ - 1);
  unsigned short* p = buf + (size_t)row * (NHT * HD) + head * HD + i4 * 2;
  union { int4 v; unsigned short u16[8]; } d;
  d.v = *(const int4*)p;
  const float4 f = *(const float4*)&fr[s * 64 + i4];
  const float fa[4] = {f.x, f.y, f.z, f.w};
#pragma unroll
  for (int i = 0; i < 4; ++i) {
    float sn, c;
    __sincosf(fa[i], &sn, &c);
    const float x0 = b2f(d.u16[2*i]), x1 = b2f(d.u16[2*i+1]);
    d.u16[2*i]   = f2b(x0 * c - x1 * sn);
    d.u16[2*i+1] = f2b(x0 * sn + x1 * c);
  }
  *(int4*)p = d.v;
}

// ---------------- GEMM: C[M,N] = A[M,K](bf16) * W[N,K]^T(bf16) ----------------
// tn-major block order: consecutive blocks share the weight panel (L2-hot),
// activations are L3-resident. Both operands staged via global_load_lds x16.
// EPI 0: +bias -> bf16 out.  EPI 1: +bias +res(f32) -> f32 out.  EPI 2: +res(f32) -> f32.
template<int EPI>
__global__ __launch_bounds__(256)
void gemm_bt(const unsigned short* __restrict__ A, const unsigned short* __restrict__ W,
             const float* __restrict__ bias, const float* __restrict__ res,
             void* __restrict__ Cout, int M, int N, int K)
{
  __shared__ unsigned short As[2][4096];   // 128 x 32
  __shared__ unsigned short Bs[2][4096];   // 128 x 32
  const int t = threadIdx.x;
  const int lane = t & 63, wid = t >> 6;
  const int wr = wid >> 1, wc = wid & 1;
  const int nbm = M >> 7;
  const int tn = blockIdx.x / nbm, tm = blockIdx.x % nbm;
  const int m0 = tm << 7, n0 = tn << 7;
  const int nk = K >> 5;
  const int srow = lane >> 2;              // row within 16-row group
  const int scol = (lane & 3) << 3;        // bf16 col offset

  auto stage = [&](int buf, int ks) {
#pragma unroll
    for (int oo = 0; oo < 2; ++oo) {
      const int o = wid * 2 + oo;
      gll16(A + (size_t)(m0 + o * 16 + srow) * K + (ks << 5) + scol, &As[buf][o * 512]);
      gll16(W + (size_t)(n0 + o * 16 + srow) * K + (ks << 5) + scol, &Bs[buf][o * 512]);
    }
  };

  f32x4_t acc[4][4];
#pragma unroll
  for (int i = 0; i < 4; ++i)
#pragma unroll
    for (int j = 0; j < 4; ++j) acc[i][j] = (f32x4_t)0.f;

  stage(0, 0);

  for (int kt = 0; kt < nk; ++kt) {
    __syncthreads();
    const int cur = kt & 1;
    if (kt + 1 < nk) stage(cur ^ 1, kt + 1);
    bf16x8_t af[4], bf[4];
#pragma unroll
    for (int mi = 0; mi < 4; ++mi)
      af[mi] = *(const bf16x8_t*)&As[cur][(wr * 64 + mi * 16 + (lane & 15)) * 32 + (lane >> 4) * 8];
#pragma unroll
    for (int ni = 0; ni < 4; ++ni)
      bf[ni] = *(const bf16x8_t*)&Bs[cur][(wc * 64 + ni * 16 + (lane & 15)) * 32 + (lane >> 4) * 8];
#pragma unroll
    for (int mi = 0; mi < 4; ++mi)
#pragma unroll
      for (int ni = 0; ni < 4; ++ni)
        acc[mi][ni] = __builtin_amdgcn_mfma_f32_16x16x32_bf16(af[mi], bf[ni], acc[mi][ni], 0, 0, 0);
  }

#pragma unroll
  for (int ni = 0; ni < 4; ++ni) {
    const int col = n0 + wc * 64 + ni * 16 + (lane & 15);
    float bv = 0.f;
    if constexpr (EPI != 2) bv = bias[col];
#pragma unroll
    for (int mi = 0; mi < 4; ++mi) {
#pragma unroll
      for (int r = 0; r < 4; ++r) {
        const int row = m0 + wr * 64 + mi * 16 + (lane >> 4) * 4 + r;
        const float vv = acc[mi][ni][r] + bv;
        if constexpr (EPI == 0) {
          ((unsigned short*)Cout)[(size_t)row * N + col] = f2b(vv);
        } else {
          ((float*)Cout)[(size_t)row * N + col] = vv + res[(size_t)row * N + col];
        }
      }
    }
  }
}

// ---------------- fused W1/W3 + SwiGLU: G = silu(A*W1^T) * (A*W3^T) -> bf16 ----------------
__global__ __launch_bounds__(256)
void gemm_w13(const unsigned short* __restrict__ A, const unsigned short* __restrict__ W1,
              const unsigned short* __restrict__ W3, unsigned short* __restrict__ G)
{
  __shared__ unsigned short As[2][4096];   // 128 x 32
  __shared__ unsigned short B1s[2][2048];  // 64 x 32
  __shared__ unsigned short B3s[2][2048];
  const int t = threadIdx.x;
  const int lane = t & 63, wid = t >> 6;
  const int wr = wid >> 1, wc = wid & 1;
  const int nbm = MTOT >> 7;               // 64
  const int tn = blockIdx.x / nbm, tm = blockIdx.x % nbm;
  const int m0 = tm << 7, n0 = tn << 6;
  const int K = DIM, nk = K >> 5;
  const int srow = lane >> 2;
  const int scol = (lane & 3) << 3;

  auto stage = [&](int buf, int ks) {
#pragma unroll
    for (int oo = 0; oo < 2; ++oo) {
      const int o = wid * 2 + oo;
      gll16(A + (size_t)(m0 + o * 16 + srow) * K + (ks << 5) + scol, &As[buf][o * 512]);
    }
    gll16(W1 + (size_t)(n0 + wid * 16 + srow) * K + (ks << 5) + scol, &B1s[buf][wid * 512]);
    gll16(W3 + (size_t)(n0 + wid * 16 + srow) * K + (ks << 5) + scol, &B3s[buf][wid * 512]);
  };

  f32x4_t acc1[4][2], acc3[4][2];
#pragma unroll
  for (int i = 0; i < 4; ++i)
#pragma unroll
    for (int j = 0; j < 2; ++j) { acc1[i][j] = (f32x4_t)0.f; acc3[i][j] = (f32x4_t)0.f; }

  stage(0, 0);

  for (int kt = 0; kt < nk; ++kt) {
    __syncthreads();
    const int cur = kt & 1;
    if (kt + 1 < nk) stage(cur ^ 1, kt + 1);
    bf16x8_t af[4], b1f[2], b3f[2];
#pragma unroll
    for (int mi = 0; mi < 4; ++mi)
      af[mi] = *(const bf16x8_t*)&As[cur][(wr * 64 + mi * 16 + (lane & 15)) * 32 + (lane >> 4) * 8];
#pragma unroll
    for (int ni = 0; ni < 2; ++ni) {
      b1f[ni] = *(const bf16x8_t*)&B1s[cur][(wc * 32 + ni * 16 + (lane & 15)) * 32 + (lane >> 4) * 8];
      b3f[ni] = *(const bf16x8_t*)&B3s[cur][(wc * 32 + ni * 16 + (lane & 15)) * 32 + (lane >> 4) * 8];
    }
#pragma unroll
    for (int mi = 0; mi < 4; ++mi)
#pragma unroll
      for (int ni = 0; ni < 2; ++ni) {
        acc1[mi][ni] = __builtin_amdgcn_mfma_f32_16x16x32_bf16(af[mi], b1f[ni], acc1[mi][ni], 0, 0, 0);
        acc3[mi][ni] = __builtin_amdgcn_mfma_f32_16x16x32_bf16(af[mi], b3f[ni], acc3[mi][ni], 0, 0, 0);
      }
  }

#pragma unroll
  for (int ni = 0; ni < 2; ++ni) {
    const int col = n0 + wc * 32 + ni * 16 + (lane & 15);
#pragma unroll
    for (int mi = 0; mi < 4; ++mi) {
#pragma unroll
      for (int r = 0; r < 4; ++r) {
        const int row = m0 + wr * 64 + mi * 16 + (lane >> 4) * 4 + r;
        const float s1 = acc1[mi][ni][r];
        const float s3 = acc3[mi][ni][r];
        const float sig = 1.f / (1.f + __expf(-s1));
        G[(size_t)row * FFNH + col] = f2b(s1 * sig * s3);
      }
    }
  }
}

// ---------------- Flash attention (non-causal, GQA 4:1) ----------------
__global__ __launch_bounds__(256)
void attn_k(const unsigned short* __restrict__ Q, const unsigned short* __restrict__ Kb,
            const unsigned short* __restrict__ Vb, unsigned short* __restrict__ O)
{
  __shared__ unsigned short Qs[8192];   // 64 x 128, XOR-swizzled
  __shared__ unsigned short Ks[4096];   // 32 x 128, XOR-swizzled
  __shared__ unsigned short Vt[4096];   // 128 x 32 (V^T), XOR-swizzled cols
  __shared__ unsigned short Ps[2048];   // per-wave 16 x 32
  const int t = threadIdx.x, lane = t & 63, wid = t >> 6;
  const int bx = blockIdx.x;
  const int qt = bx & 31, h = (bx >> 5) & 31, b = bx >> 10;
  const int kvh = h >> 2;
  const float rs = 0.08838834764831845f;   // 1/sqrt(128)

#pragma unroll
  for (int oo = 0; oo < 4; ++oo) {
    const int o = wid * 4 + oo;
    const int row = o * 4 + (lane >> 4);
    const int gl  = (lane & 15) ^ (row & 7);
    const unsigned short* gp = Q + (size_t)(b * SEQ + qt * 64 + row) * DIM + h * HD + gl * 8;
    gll16(gp, &Qs[o * 512]);
  }

  f32x4_t oa[8];
#pragma unroll
  for (int i = 0; i < 8; ++i) oa[i] = (f32x4_t)0.f;
  float mrun[4] = {-1e30f, -1e30f, -1e30f, -1e30f};
  float lrun[4] = {0.f, 0.f, 0.f, 0.f};
  const int q0 = wid * 16;

  for (int kt = 0; kt < SEQ / 32; ++kt) {
#pragma unroll
    for (int oo = 0; oo < 2; ++oo) {
      const int o = wid * 2 + oo;
      const int row = o * 4 + (lane >> 4);
      const int gl  = (lane & 15) ^ (row & 7);
      const unsigned short* gp = Kb + (size_t)(b * SEQ + kt * 32 + row) * (NKV * HD) + kvh * HD + gl * 8;
      gll16(gp, &Ks[o * 512]);
    }
    {
      const int kv = t >> 3;
      const int dc = (t & 7) << 4;
      const unsigned short* gp = Vb + (size_t)(b * SEQ + kt * 32 + kv) * (NKV * HD) + kvh * HD + dc;
      union { int4 v; unsigned short u[8]; } lo, hi;
      lo.v = *(const int4*)gp;
      hi.v = *(const int4*)(gp + 8);
      const int colv = kv ^ ((t & 3) << 3);
#pragma unroll
      for (int j = 0; j < 8; ++j) Vt[(dc + j) * 32 + colv] = lo.u[j];
#pragma unroll
      for (int j = 0; j < 8; ++j) Vt[(dc + 8 + j) * 32 + colv] = hi.u[j];
    }
    __syncthreads();

    f32x4_t sa[2];
    sa[0] = (f32x4_t)0.f; sa[1] = (f32x4_t)0.f;
    const int arow = q0 + (lane & 15);
#pragma unroll
    for (int ks = 0; ks < 4; ++ks) {
      const bf16x8_t aq = *(const bf16x8_t*)&Qs[(arow * 128 + ks * 32 + (lane >> 4) * 8) ^ ((arow & 7) << 3)];
#pragma unroll
      for (int nt = 0; nt < 2; ++nt) {
        const int krow = nt * 16 + (lane & 15);
        const bf16x8_t bk = *(const bf16x8_t*)&Ks[(krow * 128 + ks * 32 + (lane >> 4) * 8) ^ ((krow & 7) << 3)];
        sa[nt] = __builtin_amdgcn_mfma_f32_16x16x32_bf16(aq, bk, sa[nt], 0, 0, 0);
      }
    }
    float pm[4];
#pragma unroll
    for (int r = 0; r < 4; ++r) {
      float v = fmaxf(sa[0][r], sa[1][r]) * rs;
#pragma unroll
      for (int off = 1; off < 16; off <<= 1) v = fmaxf(v, __shfl_xor(v, off, 64));
      pm[r] = v;
    }
    float corr[4], mnew[4];
#pragma unroll
    for (int r = 0; r < 4; ++r) {
      mnew[r] = fmaxf(mrun[r], pm[r]);
      corr[r] = __expf(mrun[r] - mnew[r]);
      mrun[r] = mnew[r];
    }
    float pv[2][4];
#pragma unroll
    for (int nt = 0; nt < 2; ++nt)
#pragma unroll
      for (int r = 0; r < 4; ++r)
        pv[nt][r] = __expf(sa[nt][r] * rs - mnew[r]);
#pragma unroll
    for (int r = 0; r < 4; ++r) {
      float v = pv[0][r] + pv[1][r];
#pragma unroll
      for (int off = 1; off < 16; off <<= 1) v += __shfl_xor(v, off, 64);
      lrun[r] = lrun[r] * corr[r] + v;
    }
#pragma unroll
    for (int i = 0; i < 8; ++i)
#pragma unroll
      for (int r = 0; r < 4; ++r) oa[i][r] *= corr[r];

#pragma unroll
    for (int nt = 0; nt < 2; ++nt)
#pragma unroll
      for (int r = 0; r < 4; ++r)
        Ps[wid * 512 + ((lane >> 4) * 4 + r) * 32 + nt * 16 + (lane & 15)] = f2b(pv[nt][r]);
    const bf16x8_t pf = *(const bf16x8_t*)&Ps[wid * 512 + (lane & 15) * 32 + (lane >> 4) * 8];

#pragma unroll
    for (int nt2 = 0; nt2 < 8; ++nt2) {
      const bf16x8_t vf = *(const bf16x8_t*)&Vt[(nt2 * 16 + (lane & 15)) * 32 + (((lane >> 4) ^ (nt2 & 3)) << 3)];
      oa[nt2] = __builtin_amdgcn_mfma_f32_16x16x32_bf16(pf, vf, oa[nt2], 0, 0, 0);
    }
    __syncthreads();
  }

  float inv[4];
#pragma unroll
  for (int r = 0; r < 4; ++r) inv[r] = 1.f / lrun[r];
#pragma unroll
  for (int nt2 = 0; nt2 < 8; ++nt2) {
    const int col = h * HD + nt2 * 16 + (lane & 15);
#pragma unroll
    for (int r = 0; r < 4; ++r) {
      const int row = qt * 64 + q0 + (lane >> 4) * 4 + r;
      O[(size_t)(b * SEQ + row) * DIM + col] = f2b(oa[nt2][r] * inv[r]);
    }
  }
}

// ---------------- launch ----------------
extern "C" void kernel_launch(void* const* d_in, const int* in_sizes, int n_in,
                              void* d_out, int out_size, void* d_ws, size_t ws_size,
                              hipStream_t stream)
{
  (void)in_sizes; (void)n_in; (void)out_size; (void)ws_size;
  const float* x   = (const float*)d_in[0];
  const float* fr  = (const float*)d_in[1];
  const float* ga  = (const float*)d_in[3];
  const float* gf  = (const float*)d_in[4];
  const float* wq  = (const float*)d_in[5];
  const float* wqb = (const float*)d_in[6];
  const float* wk  = (const float*)d_in[7];
  const float* wkb = (const float*)d_in[8];
  const float* wv  = (const float*)d_in[9];
  const float* wvb = (const float*)d_in[10];
  const float* wo  = (const float*)d_in[11];
  const float* wob = (const float*)d_in[12];
  const float* w1  = (const float*)d_in[13];
  const float* w3  = (const float*)d_in[14];
  const float* w2  = (const float*)d_in[15];
  float* out = (float*)d_out;

  constexpr size_t MB = 1ull << 20;
  char* ws = (char*)d_ws;
  unsigned short* xn = (unsigned short*)(ws);              // [0,64) MiB
  unsigned short* qb = (unsigned short*)(ws + 64*MB);      // [64,128)
  unsigned short* kb = (unsigned short*)(ws + 128*MB);     // [128,144)
  unsigned short* vb = (unsigned short*)(ws + 144*MB);     // [144,160)
  unsigned short* ao = (unsigned short*)(ws + 160*MB);     // [160,224)
  unsigned short* hn = (unsigned short*)(ws + 224*MB);     // [224,288)
  unsigned short* g  = (unsigned short*)(ws);              // [0,172) alias (dead by FFN time)
  // JIT bf16 weight scratch, reused per phase: [288,460) MiB
  unsigned short* wscr = (unsigned short*)(ws + 288*MB);
  unsigned short* wqB = wscr;                               // 32 MiB
  unsigned short* wkB = wscr + 16*MB;                       // 8 MiB (elements are 2B)
  unsigned short* wvB = wscr + 20*MB;                       // 8 MiB
  unsigned short* woB = wscr;                               // 32 MiB (after QKV done)
  unsigned short* w1B = wscr;                               // 86 MiB
  unsigned short* w3B = wscr + 43*MB;                       // 86 MiB
  unsigned short* w2B = wscr;                               // 86 MiB

  rmsnorm_k<<<MTOT, 256, 0, stream>>>(x, ga, xn);
  cvt_bf16_k<<<(NH*HD*DIM)/2048,  256, 0, stream>>>(wq, wqB);
  cvt_bf16_k<<<(NKV*HD*DIM)/2048, 256, 0, stream>>>(wk, wkB);
  cvt_bf16_k<<<(NKV*HD*DIM)/2048, 256, 0, stream>>>(wv, wvB);
  gemm_bt<0><<<(MTOT/128)*(DIM/128),    256, 0, stream>>>(xn, wqB, wqb, nullptr, qb, MTOT, DIM,    DIM);
  gemm_bt<0><<<(MTOT/128)*(NKV*HD/128), 256, 0, stream>>>(xn, wkB, wkb, nullptr, kb, MTOT, NKV*HD, DIM);
  gemm_bt<0><<<(MTOT/128)*(NKV*HD/128), 256, 0, stream>>>(xn, wvB, wvb, nullptr, vb, MTOT, NKV*HD, DIM);
  rope_k<NH><<<(MTOT*NH*16)/256,  256, 0, stream>>>(qb, fr);
  rope_k<NKV><<<(MTOT*NKV*16)/256,256, 0, stream>>>(kb, fr);
  attn_k<<<BATCH*NH*(SEQ/64), 256, 0, stream>>>(qb, kb, vb, ao);
  cvt_bf16_k<<<(DIM*DIM)/2048, 256, 0, stream>>>(wo, woB);
  gemm_bt<1><<<(MTOT/128)*(DIM/128), 256, 0, stream>>>(ao, woB, wob, x, out, MTOT, DIM, DIM);
  rmsnorm_k<<<MTOT, 256, 0, stream>>>(out, gf, hn);
  cvt_bf16_k<<<(FFNH*DIM)/2048, 256, 0, stream>>>(w1, w1B);
  cvt_bf16_k<<<(FFNH*DIM)/2048, 256, 0, stream>>>(w3, w3B);
  gemm_w13<<<(MTOT/128)*(FFNH/64), 256, 0, stream>>>(hn, w1B, w3B, g);
  cvt_bf16_k<<<(FFNH*DIM)/2048, 256, 0, stream>>>(w2, w2B);
  gemm_bt<2><<<(MTOT/128)*(DIM/128), 256, 0, stream>>>(g, w2B, nullptr, out, out, MTOT, DIM, FFNH);
}

// Round 3
// 4334.928 us; speedup vs baseline: 1.6914x; 1.1985x over previous
//
#include <hip/hip_runtime.h>
#include <hip/hip_bf16.h>

#define DIM   4096
#define NH    32
#define NKV   8
#define HD    128
#define FFNH  11008
#define BATCH 4
#define SEQ   2048
#define MTOT  (BATCH*SEQ)   // 8192

using bf16x8_t = __attribute__((ext_vector_type(8))) short;
using f32x4_t  = __attribute__((ext_vector_type(4))) float;

typedef const __attribute__((address_space(1))) unsigned int GlbU32;
typedef __attribute__((address_space(3))) unsigned int LdsU32;

__device__ __forceinline__ unsigned short f2b(float f) {
  union { float f; unsigned int u; } v; v.f = f;
  return (unsigned short)((v.u + 0x7fffu + ((v.u >> 16) & 1u)) >> 16);
}
__device__ __forceinline__ float b2f(unsigned short b) {
  union { unsigned int u; float f; } v; v.u = ((unsigned int)b) << 16;
  return v.f;
}
__device__ __forceinline__ void gll16(const void* g, void* l) {
  __builtin_amdgcn_global_load_lds((GlbU32*)g, (LdsU32*)l, 16, 0, 0);
}

#define VM8  asm volatile("s_waitcnt vmcnt(8)" ::: "memory")
#define VM4M asm volatile("s_waitcnt vmcnt(4)" ::: "memory")
#define VM0  asm volatile("s_waitcnt vmcnt(0)" ::: "memory")

// ---------------- fp32 -> bf16 bulk convert ----------------
__global__ __launch_bounds__(256)
void cvt_bf16_k(const float* __restrict__ src, unsigned short* __restrict__ dst)
{
  const size_t i = ((size_t)blockIdx.x * 256 + threadIdx.x) * 8;
  const float4 a = *(const float4*)&src[i];
  const float4 b = *(const float4*)&src[i + 4];
  union { int4 v; unsigned short u[8]; } o;
  o.u[0] = f2b(a.x); o.u[1] = f2b(a.y); o.u[2] = f2b(a.z); o.u[3] = f2b(a.w);
  o.u[4] = f2b(b.x); o.u[5] = f2b(b.y); o.u[6] = f2b(b.z); o.u[7] = f2b(b.w);
  *(int4*)&dst[i] = o.v;
}

// ---------------- RMSNorm: fp32 in -> bf16 out ----------------
__global__ __launch_bounds__(256)
void rmsnorm_k(const float* __restrict__ X, const float* __restrict__ gamma,
               unsigned short* __restrict__ Y)
{
  const int row = blockIdx.x, t = threadIdx.x;
  const float* xr = X + (size_t)row * DIM;
  float4 v[4];
  float ss = 0.f;
#pragma unroll
  for (int p = 0; p < 4; ++p) {
    v[p] = *(const float4*)&xr[p * 1024 + t * 4];
    ss += v[p].x*v[p].x + v[p].y*v[p].y + v[p].z*v[p].z + v[p].w*v[p].w;
  }
#pragma unroll
  for (int off = 32; off >= 1; off >>= 1) ss += __shfl_xor(ss, off, 64);
  __shared__ float red[4];
  if ((t & 63) == 0) red[t >> 6] = ss;
  __syncthreads();
  const float tot = red[0] + red[1] + red[2] + red[3];
  const float rn = rsqrtf(tot * (1.f / DIM) + 1e-6f);
  unsigned short* yr = Y + (size_t)row * DIM;
#pragma unroll
  for (int p = 0; p < 4; ++p) {
    const float4 gv = *(const float4*)&gamma[p * 1024 + t * 4];
    short4 o;
    o.x = (short)f2b(v[p].x * gv.x * rn);
    o.y = (short)f2b(v[p].y * gv.y * rn);
    o.z = (short)f2b(v[p].z * gv.z * rn);
    o.w = (short)f2b(v[p].w * gv.w * rn);
    *(short4*)&yr[p * 1024 + t * 4] = o;
  }
}

// ---------------- RoPE in-place on bf16 [rows][NHT*128] ----------------
template<int NHT>
__global__ __launch_bounds__(256)
void rope_k(unsigned short* __restrict__ buf, const float* __restrict__ fr)
{
  const int u = blockIdx.x * 256 + threadIdx.x;
  const int per_row = NHT * 16;
  const int row  = u / per_row;
  const int rem  = u - row * per_row;
  const int head = rem >> 4;
  const int i4   = (rem & 15) << 2;
  const int s    = row & (SEQ - 1);
  unsigned short* p = buf + (size_t)row * (NHT * HD) + head * HD + i4 * 2;
  union { int4 v; unsigned short u16[8]; } d;
  d.v = *(const int4*)p;
  const float4 f = *(const float4*)&fr[s * 64 + i4];
  const float fa[4] = {f.x, f.y, f.z, f.w};
#pragma unroll
  for (int i = 0; i < 4; ++i) {
    float sn, c;
    __sincosf(fa[i], &sn, &c);
    const float x0 = b2f(d.u16[2*i]), x1 = b2f(d.u16[2*i+1]);
    d.u16[2*i]   = f2b(x0 * c - x1 * sn);
    d.u16[2*i+1] = f2b(x0 * sn + x1 * c);
  }
  *(int4*)p = d.v;
}

// ======================= 256x256 8-phase GEMM =======================
// MODE 0: QKV fused (+bias -> bf16 into q/k/v)
// MODE 1: O-proj (+bias +res f32 -> f32)
// MODE 2: W2 (+res f32 -> f32)
// MODE 3: W13 fused SwiGLU (-> bf16, N-tile=128 cols of G, B rows 0-127=W1, 128-255=W3)
// Structure: BK=64, ring-of-4 k32-sub-tiles per operand (128 KiB LDS), 8 waves (2M x 4N),
// per phase: 8 ds_read_b128 + 1 half-tile gll16 stage + 16 MFMA; counted vmcnt(8).
#define GP0(SLOT, STG, VM) {                                              \
  _Pragma("unroll") for (int n_ = 0; n_ < 4; ++n_) bf[n_] = rdB((SLOT), n_); \
  _Pragma("unroll") for (int m_ = 0; m_ < 4; ++m_) af[m_] = rdA((SLOT), m_ * 16); \
  STG;                                                                    \
  __builtin_amdgcn_s_barrier();                                           \
  asm volatile("s_waitcnt lgkmcnt(0)" ::: "memory");                      \
  __builtin_amdgcn_sched_barrier(0);                                      \
  __builtin_amdgcn_s_setprio(1);                                          \
  _Pragma("unroll") for (int m_ = 0; m_ < 4; ++m_)                        \
    _Pragma("unroll") for (int n_ = 0; n_ < 4; ++n_)                      \
      acc[m_][n_] = __builtin_amdgcn_mfma_f32_16x16x32_bf16(af[m_], bf[n_], acc[m_][n_], 0, 0, 0); \
  __builtin_amdgcn_s_setprio(0);                                          \
  VM;                                                                     \
  __builtin_amdgcn_s_barrier();                                           \
  __builtin_amdgcn_sched_barrier(0);                                      \
}
#define GP1(SLOT, STG, VM) {                                              \
  _Pragma("unroll") for (int m_ = 0; m_ < 4; ++m_) af[m_] = rdA((SLOT), 64 + m_ * 16); \
  STG;                                                                    \
  __builtin_amdgcn_s_barrier();                                           \
  asm volatile("s_waitcnt lgkmcnt(0)" ::: "memory");                      \
  __builtin_amdgcn_sched_barrier(0);                                      \
  __builtin_amdgcn_s_setprio(1);                                          \
  _Pragma("unroll") for (int m_ = 0; m_ < 4; ++m_)                        \
    _Pragma("unroll") for (int n_ = 0; n_ < 4; ++n_)                      \
      acc[4 + m_][n_] = __builtin_amdgcn_mfma_f32_16x16x32_bf16(af[m_], bf[n_], acc[4 + m_][n_], 0, 0, 0); \
  __builtin_amdgcn_s_setprio(0);                                          \
  VM;                                                                     \
  __builtin_amdgcn_s_barrier();                                           \
  __builtin_amdgcn_sched_barrier(0);                                      \
}

template<int MODE>
__global__ __launch_bounds__(512)
void gemm256(const unsigned short* __restrict__ A,
             const unsigned short* __restrict__ W,
             const unsigned short* __restrict__ W3p,
             const float* __restrict__ bias,
             const float* res,
             float* outF,
             unsigned short* __restrict__ outH,
             const unsigned short* __restrict__ wkp,
             const unsigned short* __restrict__ wvp,
             const float* __restrict__ bkp,
             const float* __restrict__ bvp,
             unsigned short* __restrict__ okp,
             unsigned short* __restrict__ ovp,
             int K)
{
  __shared__ __align__(16) char smem[131072];   // A ring [0,64K), B ring [64K,128K)
  const int t = threadIdx.x, lane = t & 63, wid = t >> 6;
  const int wr = wid >> 2, wc = wid & 3;        // 2M x 4N waves
  const int G = gridDim.x, bid = blockIdx.x;
  const int wg = (bid & 7) * (G >> 3) + (bid >> 3);   // XCD-chunked work order
  const int tn = wg >> 5, tm = wg & 31;               // nbm = 32 (M=8192), tm inner
  const int m0 = tm << 8;
  const int NT = K >> 6, NSUB = K >> 5;

  // B-panel pointers (P1: LDS rows 0-127, P2: rows 128-255)
  const unsigned short *P1, *P2;
  const float* bp = bias;
  unsigned short* oh = outH;
  int nloc = 0, colsN = 4096;
  if constexpr (MODE == 0) {
    const int n0 = tn << 8;
    if (n0 < 4096)      { nloc = n0;        P1 = W   + (size_t)nloc * K; bp = bias; oh = outH; colsN = 4096; }
    else if (n0 < 5120) { nloc = n0 - 4096; P1 = wkp + (size_t)nloc * K; bp = bkp;  oh = okp;  colsN = 1024; }
    else                { nloc = n0 - 5120; P1 = wvp + (size_t)nloc * K; bp = bvp;  oh = ovp;  colsN = 1024; }
    P2 = P1 + (size_t)128 * K;
  } else if constexpr (MODE == 3) {
    const int n0w = tn << 7;
    P1 = W   + (size_t)n0w * K;
    P2 = W3p + (size_t)n0w * K;
    nloc = n0w;
  } else {
    const int n0 = tn << 8;
    P1 = W + (size_t)n0 * K;
    P2 = P1 + (size_t)128 * K;
    nloc = n0;
  }

  const int r0 = t >> 2, gg = t & 3;            // staging row/granule
  const int gsw = gg ^ ((r0 >> 1) & 3);         // source-swizzled granule (rows repeat mod 8)

  auto stA = [&](int sig) {
    if (sig < NSUB) {
      const int slot = sig & 3;
      gll16(A + (size_t)(m0 + r0) * K + sig * 32 + gsw * 8,
            smem + slot * 16384 + wid * 1024);
      gll16(A + (size_t)(m0 + 128 + r0) * K + sig * 32 + gsw * 8,
            smem + slot * 16384 + 8192 + wid * 1024);
    }
  };
  auto stB = [&](int sig) {
    if (sig < NSUB) {
      const int slot = sig & 3;
      gll16(P1 + (size_t)r0 * K + sig * 32 + gsw * 8,
            smem + 65536 + slot * 16384 + wid * 1024);
      gll16(P2 + (size_t)r0 * K + sig * 32 + gsw * 8,
            smem + 65536 + slot * 16384 + 8192 + wid * 1024);
    }
  };
  auto rdA = [&](int slot, int mo) -> bf16x8_t {
    const int lrow = wr * 128 + mo + (lane & 15);
    const int g = (lane >> 4) ^ ((lrow >> 1) & 3);
    return *(const bf16x8_t*)(smem + slot * 16384 + lrow * 64 + g * 16);
  };
  auto rdB = [&](int slot, int nf) -> bf16x8_t {
    const int brow = wc * 64 + nf * 16 + (lane & 15);
    const int g = (lane >> 4) ^ ((brow >> 1) & 3);
    return *(const bf16x8_t*)(smem + 65536 + slot * 16384 + brow * 64 + g * 16);
  };

  f32x4_t acc[8][4];
#pragma unroll
  for (int i = 0; i < 8; ++i)
#pragma unroll
    for (int j = 0; j < 4; ++j) acc[i][j] = (f32x4_t)0.f;
  bf16x8_t af[4], bf[4];

  // prologue: sub-tiles 0,1,2 for A and B; assure sigma0 landed
  stA(0); stB(0); stA(1); stB(1); stA(2); stB(2);
  VM8;
  __builtin_amdgcn_s_barrier();
  __builtin_amdgcn_sched_barrier(0);

  for (int kt = 0; kt < NT; ++kt) {
    const int slot0 = (2 * kt) & 3;
    const int slot1 = slot0 + 1;
    GP0(slot0, stA(2 * kt + 3), (void)0);
    GP1(slot0, stB(2 * kt + 3), if (kt < NT - 1) { VM8; } else { VM0; });
    GP0(slot1, stA(2 * kt + 4), (void)0);
    GP1(slot1, stB(2 * kt + 4), if (kt < NT - 2) { VM8; } else { VM4M; });
  }

  // ---------------- epilogue ----------------
  if constexpr (MODE == 0) {
#pragma unroll
    for (int ni = 0; ni < 4; ++ni) {
      const int col = nloc + wc * 64 + ni * 16 + (lane & 15);
      const float bv = bp[col];
#pragma unroll
      for (int mi = 0; mi < 8; ++mi)
#pragma unroll
        for (int r = 0; r < 4; ++r) {
          const int row = m0 + wr * 128 + mi * 16 + (lane >> 4) * 4 + r;
          oh[(size_t)row * colsN + col] = f2b(acc[mi][ni][r] + bv);
        }
    }
  } else if constexpr (MODE == 1 || MODE == 2) {
#pragma unroll
    for (int ni = 0; ni < 4; ++ni) {
      const int col = nloc + wc * 64 + ni * 16 + (lane & 15);
      float bv = 0.f;
      if constexpr (MODE == 1) bv = bias[col];
#pragma unroll
      for (int mi = 0; mi < 8; ++mi)
#pragma unroll
        for (int r = 0; r < 4; ++r) {
          const int row = m0 + wr * 128 + mi * 16 + (lane >> 4) * 4 + r;
          const size_t idx = (size_t)row * 4096 + col;
          outF[idx] = acc[mi][ni][r] + bv + res[idx];
        }
    }
  } else {
    // W13: waves wc>=2 hold s3; exchange via LDS (bf16), waves wc<2 do SwiGLU
    if (wc >= 2) {
      const int widx = wr * 2 + (wc - 2);
#pragma unroll
      for (int ni = 0; ni < 4; ++ni)
#pragma unroll
        for (int mi = 0; mi < 8; ++mi)
#pragma unroll
          for (int r = 0; r < 4; ++r) {
            const int lrow = mi * 16 + (lane >> 4) * 4 + r;
            const int ncol = ni * 16 + (lane & 15);
            *(unsigned short*)(smem + widx * 16384 + lrow * 128 + ncol * 2) =
                f2b(acc[mi][ni][r]);
          }
    }
    __syncthreads();
    if (wc < 2) {
      const int widx = wr * 2 + wc;
#pragma unroll
      for (int ni = 0; ni < 4; ++ni)
#pragma unroll
        for (int mi = 0; mi < 8; ++mi)
#pragma unroll
          for (int r = 0; r < 4; ++r) {
            const int lrow = mi * 16 + (lane >> 4) * 4 + r;
            const int ncol = ni * 16 + (lane & 15);
            const float s3 = b2f(*(const unsigned short*)(smem + widx * 16384 + lrow * 128 + ncol * 2));
            const float s1 = acc[mi][ni][r];
            const float sig = 1.f / (1.f + __expf(-s1));
            const int row = m0 + wr * 128 + lrow;
            outH[(size_t)row * FFNH + nloc + wc * 64 + ncol] = f2b(s1 * sig * s3);
          }
    }
  }
}

// ---------------- Flash attention (non-causal, GQA 4:1) ----------------
__global__ __launch_bounds__(256)
void attn_k(const unsigned short* __restrict__ Q, const unsigned short* __restrict__ Kb,
            const unsigned short* __restrict__ Vb, unsigned short* __restrict__ O)
{
  __shared__ unsigned short Qs[8192];
  __shared__ unsigned short Ks[4096];
  __shared__ unsigned short Vt[4096];
  __shared__ unsigned short Ps[2048];
  const int t = threadIdx.x, lane = t & 63, wid = t >> 6;
  const int bx = blockIdx.x;
  const int qt = bx & 31, h = (bx >> 5) & 31, b = bx >> 10;
  const int kvh = h >> 2;
  const float rs = 0.08838834764831845f;

#pragma unroll
  for (int oo = 0; oo < 4; ++oo) {
    const int o = wid * 4 + oo;
    const int row = o * 4 + (lane >> 4);
    const int gl  = (lane & 15) ^ (row & 7);
    const unsigned short* gp = Q + (size_t)(b * SEQ + qt * 64 + row) * DIM + h * HD + gl * 8;
    gll16(gp, &Qs[o * 512]);
  }

  f32x4_t oa[8];
#pragma unroll
  for (int i = 0; i < 8; ++i) oa[i] = (f32x4_t)0.f;
  float mrun[4] = {-1e30f, -1e30f, -1e30f, -1e30f};
  float lrun[4] = {0.f, 0.f, 0.f, 0.f};
  const int q0 = wid * 16;

  for (int kt = 0; kt < SEQ / 32; ++kt) {
#pragma unroll
    for (int oo = 0; oo < 2; ++oo) {
      const int o = wid * 2 + oo;
      const int row = o * 4 + (lane >> 4);
      const int gl  = (lane & 15) ^ (row & 7);
      const unsigned short* gp = Kb + (size_t)(b * SEQ + kt * 32 + row) * (NKV * HD) + kvh * HD + gl * 8;
      gll16(gp, &Ks[o * 512]);
    }
    {
      const int kv = t >> 3;
      const int dc = (t & 7) << 4;
      const unsigned short* gp = Vb + (size_t)(b * SEQ + kt * 32 + kv) * (NKV * HD) + kvh * HD + dc;
      union { int4 v; unsigned short u[8]; } lo, hi;
      lo.v = *(const int4*)gp;
      hi.v = *(const int4*)(gp + 8);
      const int colv = kv ^ ((t & 3) << 3);
#pragma unroll
      for (int j = 0; j < 8; ++j) Vt[(dc + j) * 32 + colv] = lo.u[j];
#pragma unroll
      for (int j = 0; j < 8; ++j) Vt[(dc + 8 + j) * 32 + colv] = hi.u[j];
    }
    __syncthreads();

    f32x4_t sa[2];
    sa[0] = (f32x4_t)0.f; sa[1] = (f32x4_t)0.f;
    const int arow = q0 + (lane & 15);
#pragma unroll
    for (int ks = 0; ks < 4; ++ks) {
      const bf16x8_t aq = *(const bf16x8_t*)&Qs[(arow * 128 + ks * 32 + (lane >> 4) * 8) ^ ((arow & 7) << 3)];
#pragma unroll
      for (int nt = 0; nt < 2; ++nt) {
        const int krow = nt * 16 + (lane & 15);
        const bf16x8_t bk = *(const bf16x8_t*)&Ks[(krow * 128 + ks * 32 + (lane >> 4) * 8) ^ ((krow & 7) << 3)];
        sa[nt] = __builtin_amdgcn_mfma_f32_16x16x32_bf16(aq, bk, sa[nt], 0, 0, 0);
      }
    }
    float pm[4];
#pragma unroll
    for (int r = 0; r < 4; ++r) {
      float v = fmaxf(sa[0][r], sa[1][r]) * rs;
#pragma unroll
      for (int off = 1; off < 16; off <<= 1) v = fmaxf(v, __shfl_xor(v, off, 64));
      pm[r] = v;
    }
    float corr[4], mnew[4];
#pragma unroll
    for (int r = 0; r < 4; ++r) {
      mnew[r] = fmaxf(mrun[r], pm[r]);
      corr[r] = __expf(mrun[r] - mnew[r]);
      mrun[r] = mnew[r];
    }
    float pv[2][4];
#pragma unroll
    for (int nt = 0; nt < 2; ++nt)
#pragma unroll
      for (int r = 0; r < 4; ++r)
        pv[nt][r] = __expf(sa[nt][r] * rs - mnew[r]);
#pragma unroll
    for (int r = 0; r < 4; ++r) {
      float v = pv[0][r] + pv[1][r];
#pragma unroll
      for (int off = 1; off < 16; off <<= 1) v += __shfl_xor(v, off, 64);
      lrun[r] = lrun[r] * corr[r] + v;
    }
#pragma unroll
    for (int i = 0; i < 8; ++i)
#pragma unroll
      for (int r = 0; r < 4; ++r) oa[i][r] *= corr[r];

#pragma unroll
    for (int nt = 0; nt < 2; ++nt)
#pragma unroll
      for (int r = 0; r < 4; ++r)
        Ps[wid * 512 + ((lane >> 4) * 4 + r) * 32 + nt * 16 + (lane & 15)] = f2b(pv[nt][r]);
    const bf16x8_t pf = *(const bf16x8_t*)&Ps[wid * 512 + (lane & 15) * 32 + (lane >> 4) * 8];

#pragma unroll
    for (int nt2 = 0; nt2 < 8; ++nt2) {
      const bf16x8_t vf = *(const bf16x8_t*)&Vt[(nt2 * 16 + (lane & 15)) * 32 + (((lane >> 4) ^ (nt2 & 3)) << 3)];
      oa[nt2] = __builtin_amdgcn_mfma_f32_16x16x32_bf16(pf, vf, oa[nt2], 0, 0, 0);
    }
    __syncthreads();
  }

  float inv[4];
#pragma unroll
  for (int r = 0; r < 4; ++r) inv[r] = 1.f / lrun[r];
#pragma unroll
  for (int nt2 = 0; nt2 < 8; ++nt2) {
    const int col = h * HD + nt2 * 16 + (lane & 15);
#pragma unroll
    for (int r = 0; r < 4; ++r) {
      const int row = qt * 64 + q0 + (lane >> 4) * 4 + r;
      O[(size_t)(b * SEQ + row) * DIM + col] = f2b(oa[nt2][r] * inv[r]);
    }
  }
}

// ---------------- launch ----------------
extern "C" void kernel_launch(void* const* d_in, const int* in_sizes, int n_in,
                              void* d_out, int out_size, void* d_ws, size_t ws_size,
                              hipStream_t stream)
{
  (void)in_sizes; (void)n_in; (void)out_size; (void)ws_size;
  const float* x   = (const float*)d_in[0];
  const float* fr  = (const float*)d_in[1];
  const float* ga  = (const float*)d_in[3];
  const float* gf  = (const float*)d_in[4];
  const float* wq  = (const float*)d_in[5];
  const float* wqb = (const float*)d_in[6];
  const float* wk  = (const float*)d_in[7];
  const float* wkb = (const float*)d_in[8];
  const float* wv  = (const float*)d_in[9];
  const float* wvb = (const float*)d_in[10];
  const float* wo  = (const float*)d_in[11];
  const float* wob = (const float*)d_in[12];
  const float* w1  = (const float*)d_in[13];
  const float* w3  = (const float*)d_in[14];
  const float* w2  = (const float*)d_in[15];
  float* out = (float*)d_out;

  constexpr size_t MB = 1ull << 20;
  char* ws = (char*)d_ws;
  unsigned short* xn = (unsigned short*)(ws);              // [0,64) MiB
  unsigned short* qb = (unsigned short*)(ws + 64*MB);      // [64,128)
  unsigned short* kb = (unsigned short*)(ws + 128*MB);     // [128,144)
  unsigned short* vb = (unsigned short*)(ws + 144*MB);     // [144,160)
  unsigned short* ao = (unsigned short*)(ws + 160*MB);     // [160,224)
  unsigned short* hn = (unsigned short*)(ws + 224*MB);     // [224,288)
  unsigned short* g  = (unsigned short*)(ws);              // [0,172) alias (dead by FFN time)
  unsigned short* wscr = (unsigned short*)(ws + 288*MB);   // JIT bf16 weights
  unsigned short* wqB = wscr;                               // 32 MiB
  unsigned short* wkB = wscr + 16*MB;                       // 8 MiB
  unsigned short* wvB = wscr + 20*MB;                       // 8 MiB
  unsigned short* woB = wscr;                               // 32 MiB (after QKV)
  unsigned short* w1B = wscr;                               // 90 MiB
  unsigned short* w3B = wscr + 45*MB;                       // 90 MiB
  unsigned short* w2B = wscr;                               // 90 MiB

  rmsnorm_k<<<MTOT, 256, 0, stream>>>(x, ga, xn);
  cvt_bf16_k<<<(NH*HD*DIM)/2048,  256, 0, stream>>>(wq, wqB);
  cvt_bf16_k<<<(NKV*HD*DIM)/2048, 256, 0, stream>>>(wk, wkB);
  cvt_bf16_k<<<(NKV*HD*DIM)/2048, 256, 0, stream>>>(wv, wvB);
  gemm256<0><<<(MTOT/256)*((DIM+2*NKV*HD)/256), 512, 0, stream>>>(
      xn, wqB, nullptr, wqb, nullptr, nullptr, qb,
      wkB, wvB, wkb, wvb, kb, vb, DIM);
  rope_k<NH><<<(MTOT*NH*16)/256,  256, 0, stream>>>(qb, fr);
  rope_k<NKV><<<(MTOT*NKV*16)/256,256, 0, stream>>>(kb, fr);
  attn_k<<<BATCH*NH*(SEQ/64), 256, 0, stream>>>(qb, kb, vb, ao);
  cvt_bf16_k<<<(DIM*DIM)/2048, 256, 0, stream>>>(wo, woB);
  gemm256<1><<<(MTOT/256)*(DIM/256), 512, 0, stream>>>(
      ao, woB, nullptr, wob, x, out, nullptr,
      nullptr, nullptr, nullptr, nullptr, nullptr, nullptr, DIM);
  rmsnorm_k<<<MTOT, 256, 0, stream>>>(out, gf, hn);
  cvt_bf16_k<<<(FFNH*DIM)/2048, 256, 0, stream>>>(w1, w1B);
  cvt_bf16_k<<<(FFNH*DIM)/2048, 256, 0, stream>>>(w3, w3B);
  gemm256<3><<<(MTOT/256)*(FFNH/128), 512, 0, stream>>>(
      hn, w1B, w3B, nullptr, nullptr, nullptr, g,
      nullptr, nullptr, nullptr, nullptr, nullptr, nullptr, DIM);
  cvt_bf16_k<<<(FFNH*DIM)/2048, 256, 0, stream>>>(w2, w2B);
  gemm256<2><<<(MTOT/256)*(DIM/256), 512, 0, stream>>>(
      g, w2B, nullptr, nullptr, out, out, nullptr,
      nullptr, nullptr, nullptr, nullptr, nullptr, nullptr, FFNH);
}

// Round 4
// 4196.626 us; speedup vs baseline: 1.7471x; 1.0330x over previous
//
#include <hip/hip_runtime.h>
#include <hip/hip_bf16.h>

#define DIM   4096
#define NH    32
#define NKV   8
#define HD    128
#define FFNH  11008
#define BATCH 4
#define SEQ   2048
#define MTOT  (BATCH*SEQ)   // 8192

using bf16x8_t = __attribute__((ext_vector_type(8))) short;
using f32x4_t  = __attribute__((ext_vector_type(4))) float;

typedef const __attribute__((address_space(1))) unsigned int GlbU32;
typedef __attribute__((address_space(3))) unsigned int LdsU32;

__device__ __forceinline__ unsigned short f2b(float f) {
  union { float f; unsigned int u; } v; v.f = f;
  return (unsigned short)((v.u + 0x7fffu + ((v.u >> 16) & 1u)) >> 16);
}
__device__ __forceinline__ float b2f(unsigned short b) {
  union { unsigned int u; float f; } v; v.u = ((unsigned int)b) << 16;
  return v.f;
}
__device__ __forceinline__ void gll16(const void* g, void* l) {
  __builtin_amdgcn_global_load_lds((GlbU32*)g, (LdsU32*)l, 16, 0, 0);
}

#define VM8  asm volatile("s_waitcnt vmcnt(8)" ::: "memory")
#define VM4M asm volatile("s_waitcnt vmcnt(4)" ::: "memory")
#define VM0  asm volatile("s_waitcnt vmcnt(0)" ::: "memory")

// ---------------- fp32 -> bf16 bulk convert ----------------
__global__ __launch_bounds__(256)
void cvt_bf16_k(const float* __restrict__ src, unsigned short* __restrict__ dst)
{
  const size_t i = ((size_t)blockIdx.x * 256 + threadIdx.x) * 8;
  const float4 a = *(const float4*)&src[i];
  const float4 b = *(const float4*)&src[i + 4];
  union { int4 v; unsigned short u[8]; } o;
  o.u[0] = f2b(a.x); o.u[1] = f2b(a.y); o.u[2] = f2b(a.z); o.u[3] = f2b(a.w);
  o.u[4] = f2b(b.x); o.u[5] = f2b(b.y); o.u[6] = f2b(b.z); o.u[7] = f2b(b.w);
  *(int4*)&dst[i] = o.v;
}

// ---------------- RMSNorm: fp32 in -> bf16 out ----------------
__global__ __launch_bounds__(256)
void rmsnorm_k(const float* __restrict__ X, const float* __restrict__ gamma,
               unsigned short* __restrict__ Y)
{
  const int row = blockIdx.x, t = threadIdx.x;
  const float* xr = X + (size_t)row * DIM;
  float4 v[4];
  float ss = 0.f;
#pragma unroll
  for (int p = 0; p < 4; ++p) {
    v[p] = *(const float4*)&xr[p * 1024 + t * 4];
    ss += v[p].x*v[p].x + v[p].y*v[p].y + v[p].z*v[p].z + v[p].w*v[p].w;
  }
#pragma unroll
  for (int off = 32; off >= 1; off >>= 1) ss += __shfl_xor(ss, off, 64);
  __shared__ float red[4];
  if ((t & 63) == 0) red[t >> 6] = ss;
  __syncthreads();
  const float tot = red[0] + red[1] + red[2] + red[3];
  const float rn = rsqrtf(tot * (1.f / DIM) + 1e-6f);
  unsigned short* yr = Y + (size_t)row * DIM;
#pragma unroll
  for (int p = 0; p < 4; ++p) {
    const float4 gv = *(const float4*)&gamma[p * 1024 + t * 4];
    short4 o;
    o.x = (short)f2b(v[p].x * gv.x * rn);
    o.y = (short)f2b(v[p].y * gv.y * rn);
    o.z = (short)f2b(v[p].z * gv.z * rn);
    o.w = (short)f2b(v[p].w * gv.w * rn);
    *(short4*)&yr[p * 1024 + t * 4] = o;
  }
}

// ---------------- RoPE in-place on bf16 [rows][NHT*128] ----------------
template<int NHT>
__global__ __launch_bounds__(256)
void rope_k(unsigned short* __restrict__ buf, const float* __restrict__ fr)
{
  const int u = blockIdx.x * 256 + threadIdx.x;
  const int per_row = NHT * 16;
  const int row  = u / per_row;
  const int rem  = u - row * per_row;
  const int head = rem >> 4;
  const int i4   = (rem & 15) << 2;
  const int s    = row & (SEQ - 1);
  unsigned short* p = buf + (size_t)row * (NHT * HD) + head * HD + i4 * 2;
  union { int4 v; unsigned short u16[8]; } d;
  d.v = *(const int4*)p;
  const float4 f = *(const float4*)&fr[s * 64 + i4];
  const float fa[4] = {f.x, f.y, f.z, f.w};
#pragma unroll
  for (int i = 0; i < 4; ++i) {
    float sn, c;
    __sincosf(fa[i], &sn, &c);
    const float x0 = b2f(d.u16[2*i]), x1 = b2f(d.u16[2*i+1]);
    d.u16[2*i]   = f2b(x0 * c - x1 * sn);
    d.u16[2*i+1] = f2b(x0 * sn + x1 * c);
  }
  *(int4*)p = d.v;
}

// ======================= 256x256 8-phase GEMM =======================
// MODE 0: QKV fused (+bias -> bf16 into q/k/v)
// MODE 1: O-proj (+bias +res f32 -> f32)
// MODE 2: W2 (+res f32 -> f32)  [tn-INNER order: weights (90MB, L3-resident) re-streamed;
//          A=G (180MB) read once -> kills the 3.3GB HBM re-stream seen in round 3]
// MODE 3: W13 fused SwiGLU (-> bf16)
#define GP0(SLOT, STG, VM) {                                              \
  _Pragma("unroll") for (int n_ = 0; n_ < 4; ++n_) bf[n_] = rdB((SLOT), n_); \
  _Pragma("unroll") for (int m_ = 0; m_ < 4; ++m_) af[m_] = rdA((SLOT), m_ * 16); \
  STG;                                                                    \
  __builtin_amdgcn_s_barrier();                                           \
  asm volatile("s_waitcnt lgkmcnt(0)" ::: "memory");                      \
  __builtin_amdgcn_sched_barrier(0);                                      \
  __builtin_amdgcn_s_setprio(1);                                          \
  _Pragma("unroll") for (int m_ = 0; m_ < 4; ++m_)                        \
    _Pragma("unroll") for (int n_ = 0; n_ < 4; ++n_)                      \
      acc[m_][n_] = __builtin_amdgcn_mfma_f32_16x16x32_bf16(af[m_], bf[n_], acc[m_][n_], 0, 0, 0); \
  __builtin_amdgcn_s_setprio(0);                                          \
  VM;                                                                     \
  __builtin_amdgcn_s_barrier();                                           \
  __builtin_amdgcn_sched_barrier(0);                                      \
}
#define GP1(SLOT, STG, VM) {                                              \
  _Pragma("unroll") for (int m_ = 0; m_ < 4; ++m_) af[m_] = rdA((SLOT), 64 + m_ * 16); \
  STG;                                                                    \
  __builtin_amdgcn_s_barrier();                                           \
  asm volatile("s_waitcnt lgkmcnt(0)" ::: "memory");                      \
  __builtin_amdgcn_sched_barrier(0);                                      \
  __builtin_amdgcn_s_setprio(1);                                          \
  _Pragma("unroll") for (int m_ = 0; m_ < 4; ++m_)                        \
    _Pragma("unroll") for (int n_ = 0; n_ < 4; ++n_)                      \
      acc[4 + m_][n_] = __builtin_amdgcn_mfma_f32_16x16x32_bf16(af[m_], bf[n_], acc[4 + m_][n_], 0, 0, 0); \
  __builtin_amdgcn_s_setprio(0);                                          \
  VM;                                                                     \
  __builtin_amdgcn_s_barrier();                                           \
  __builtin_amdgcn_sched_barrier(0);                                      \
}

template<int MODE>
__global__ __launch_bounds__(512)
void gemm256(const unsigned short* __restrict__ A,
             const unsigned short* __restrict__ W,
             const unsigned short* __restrict__ W3p,
             const float* __restrict__ bias,
             const float* res,
             float* outF,
             unsigned short* __restrict__ outH,
             const unsigned short* __restrict__ wkp,
             const unsigned short* __restrict__ wvp,
             const float* __restrict__ bkp,
             const float* __restrict__ bvp,
             unsigned short* __restrict__ okp,
             unsigned short* __restrict__ ovp,
             int K)
{
  __shared__ __align__(16) char smem[131072];
  const int t = threadIdx.x, lane = t & 63, wid = t >> 6;
  const int wr = wid >> 2, wc = wid & 3;
  const int G = gridDim.x, bid = blockIdx.x;
  const int wg = (bid & 7) * (G >> 3) + (bid >> 3);   // XCD-chunked work order
  int tn, tm;
  if constexpr (MODE == 2) { tm = wg >> 4; tn = wg & 15; }  // tn-inner: weights re-streamed
  else                     { tn = wg >> 5; tm = wg & 31; }  // tm-inner: A re-streamed
  const int m0 = tm << 8;
  const int NT = K >> 6, NSUB = K >> 5;

  const unsigned short *P1, *P2;
  const float* bp = bias;
  unsigned short* oh = outH;
  int nloc = 0, colsN = 4096;
  if constexpr (MODE == 0) {
    const int n0 = tn << 8;
    if (n0 < 4096)      { nloc = n0;        P1 = W   + (size_t)nloc * K; bp = bias; oh = outH; colsN = 4096; }
    else if (n0 < 5120) { nloc = n0 - 4096; P1 = wkp + (size_t)nloc * K; bp = bkp;  oh = okp;  colsN = 1024; }
    else                { nloc = n0 - 5120; P1 = wvp + (size_t)nloc * K; bp = bvp;  oh = ovp;  colsN = 1024; }
    P2 = P1 + (size_t)128 * K;
  } else if constexpr (MODE == 3) {
    const int n0w = tn << 7;
    P1 = W   + (size_t)n0w * K;
    P2 = W3p + (size_t)n0w * K;
    nloc = n0w;
  } else {
    const int n0 = tn << 8;
    P1 = W + (size_t)n0 * K;
    P2 = P1 + (size_t)128 * K;
    nloc = n0;
  }

  const int r0 = t >> 2, gg = t & 3;
  const int gsw = gg ^ ((r0 >> 1) & 3);

  auto stA = [&](int sig) {
    if (sig < NSUB) {
      const int slot = sig & 3;
      gll16(A + (size_t)(m0 + r0) * K + sig * 32 + gsw * 8,
            smem + slot * 16384 + wid * 1024);
      gll16(A + (size_t)(m0 + 128 + r0) * K + sig * 32 + gsw * 8,
            smem + slot * 16384 + 8192 + wid * 1024);
    }
  };
  auto stB = [&](int sig) {
    if (sig < NSUB) {
      const int slot = sig & 3;
      gll16(P1 + (size_t)r0 * K + sig * 32 + gsw * 8,
            smem + 65536 + slot * 16384 + wid * 1024);
      gll16(P2 + (size_t)r0 * K + sig * 32 + gsw * 8,
            smem + 65536 + slot * 16384 + 8192 + wid * 1024);
    }
  };
  auto rdA = [&](int slot, int mo) -> bf16x8_t {
    const int lrow = wr * 128 + mo + (lane & 15);
    const int g = (lane >> 4) ^ ((lrow >> 1) & 3);
    return *(const bf16x8_t*)(smem + slot * 16384 + lrow * 64 + g * 16);
  };
  auto rdB = [&](int slot, int nf) -> bf16x8_t {
    const int brow = wc * 64 + nf * 16 + (lane & 15);
    const int g = (lane >> 4) ^ ((brow >> 1) & 3);
    return *(const bf16x8_t*)(smem + 65536 + slot * 16384 + brow * 64 + g * 16);
  };

  f32x4_t acc[8][4];
#pragma unroll
  for (int i = 0; i < 8; ++i)
#pragma unroll
    for (int j = 0; j < 4; ++j) acc[i][j] = (f32x4_t)0.f;
  bf16x8_t af[4], bf[4];

  stA(0); stB(0); stA(1); stB(1); stA(2); stB(2);
  VM8;
  __builtin_amdgcn_s_barrier();
  __builtin_amdgcn_sched_barrier(0);

  for (int kt = 0; kt < NT; ++kt) {
    const int slot0 = (2 * kt) & 3;
    const int slot1 = slot0 + 1;
    GP0(slot0, stA(2 * kt + 3), (void)0);
    GP1(slot0, stB(2 * kt + 3), if (kt < NT - 1) { VM8; } else { VM0; });
    GP0(slot1, stA(2 * kt + 4), (void)0);
    GP1(slot1, stB(2 * kt + 4), if (kt < NT - 2) { VM8; } else { VM4M; });
  }

  if constexpr (MODE == 0) {
#pragma unroll
    for (int ni = 0; ni < 4; ++ni) {
      const int col = nloc + wc * 64 + ni * 16 + (lane & 15);
      const float bv = bp[col];
#pragma unroll
      for (int mi = 0; mi < 8; ++mi)
#pragma unroll
        for (int r = 0; r < 4; ++r) {
          const int row = m0 + wr * 128 + mi * 16 + (lane >> 4) * 4 + r;
          oh[(size_t)row * colsN + col] = f2b(acc[mi][ni][r] + bv);
        }
    }
  } else if constexpr (MODE == 1 || MODE == 2) {
#pragma unroll
    for (int ni = 0; ni < 4; ++ni) {
      const int col = nloc + wc * 64 + ni * 16 + (lane & 15);
      float bv = 0.f;
      if constexpr (MODE == 1) bv = bias[col];
#pragma unroll
      for (int mi = 0; mi < 8; ++mi)
#pragma unroll
        for (int r = 0; r < 4; ++r) {
          const int row = m0 + wr * 128 + mi * 16 + (lane >> 4) * 4 + r;
          const size_t idx = (size_t)row * 4096 + col;
          outF[idx] = acc[mi][ni][r] + bv + res[idx];
        }
    }
  } else {
    if (wc >= 2) {
      const int widx = wr * 2 + (wc - 2);
#pragma unroll
      for (int ni = 0; ni < 4; ++ni)
#pragma unroll
        for (int mi = 0; mi < 8; ++mi)
#pragma unroll
          for (int r = 0; r < 4; ++r) {
            const int lrow = mi * 16 + (lane >> 4) * 4 + r;
            const int ncol = ni * 16 + (lane & 15);
            *(unsigned short*)(smem + widx * 16384 + lrow * 128 + ncol * 2) =
                f2b(acc[mi][ni][r]);
          }
    }
    __syncthreads();
    if (wc < 2) {
      const int widx = wr * 2 + wc;
#pragma unroll
      for (int ni = 0; ni < 4; ++ni)
#pragma unroll
        for (int mi = 0; mi < 8; ++mi)
#pragma unroll
          for (int r = 0; r < 4; ++r) {
            const int lrow = mi * 16 + (lane >> 4) * 4 + r;
            const int ncol = ni * 16 + (lane & 15);
            const float s3 = b2f(*(const unsigned short*)(smem + widx * 16384 + lrow * 128 + ncol * 2));
            const float s1 = acc[mi][ni][r];
            const float sig = 1.f / (1.f + __expf(-s1));
            const int row = m0 + wr * 128 + lrow;
            outH[(size_t)row * FFNH + nloc + wc * 64 + ncol] = f2b(s1 * sig * s3);
          }
    }
  }
}

// ---------------- Flash attention (non-causal, GQA 4:1) ----------------
// 2-deep pipelined K/V staging, counted vmcnt(4), raw barriers (no vmcnt(0) drain).
__global__ __launch_bounds__(256)
void attn_k(const unsigned short* __restrict__ Q, const unsigned short* __restrict__ Kb,
            const unsigned short* __restrict__ Vb, unsigned short* __restrict__ O)
{
  __shared__ unsigned short Qs[8192];      // 64x128 swizzled
  __shared__ unsigned short Ks[2][4096];   // 32x128 swizzled, ring-2
  __shared__ unsigned short Vt[2][4096];   // 128x32 V^T col-swizzled, ring-2
  __shared__ unsigned short Ps[2048];      // per-wave 16x32
  const int t = threadIdx.x, lane = t & 63, wid = t >> 6;
  const int bx = blockIdx.x;
  const int qt = bx & 31, h = (bx >> 5) & 31, b = bx >> 10;
  const int kvh = h >> 2;
  const float rs = 0.08838834764831845f;

#pragma unroll
  for (int oo = 0; oo < 4; ++oo) {
    const int o = wid * 4 + oo;
    const int row = o * 4 + (lane >> 4);
    const int gl  = (lane & 15) ^ (row & 7);
    gll16(Q + (size_t)(b * SEQ + qt * 64 + row) * DIM + h * HD + gl * 8, &Qs[o * 512]);
  }

  const unsigned short* Kbase = Kb + (size_t)(b * SEQ) * (NKV * HD) + kvh * HD;
  const unsigned short* Vbase = Vb + (size_t)(b * SEQ) * (NKV * HD) + kvh * HD;

  auto stK = [&](int kt, int slot) {
#pragma unroll
    for (int oo = 0; oo < 2; ++oo) {
      const int o = wid * 2 + oo;
      const int row = o * 4 + (lane >> 4);
      const int gl  = (lane & 15) ^ (row & 7);
      gll16(Kbase + (size_t)(kt * 32 + row) * (NKV * HD) + gl * 8, &Ks[slot][o * 512]);
    }
  };
  const int kv = t >> 3, dc = (t & 7) << 4;
  const int colv = kv ^ ((t & 3) << 3);
  auto ldV = [&](int kt, int4& lo, int4& hi) {
    const unsigned short* gp = Vbase + (size_t)(kt * 32 + kv) * (NKV * HD) + dc;
    lo = *(const int4*)gp;
    hi = *(const int4*)(gp + 8);
  };

  int4 vlo0, vhi0, vlo1, vhi1;
  stK(0, 0); ldV(0, vlo0, vhi0);
  stK(1, 1); ldV(1, vlo1, vhi1);

  f32x4_t oa[8];
#pragma unroll
  for (int i = 0; i < 8; ++i) oa[i] = (f32x4_t)0.f;
  float mrun[4] = {-1e30f, -1e30f, -1e30f, -1e30f};
  float lrun[4] = {0.f, 0.f, 0.f, 0.f};
  const int q0 = wid * 16;

  auto iter = [&](int kt, int cur, int4& vlo, int4& vhi) {
    asm volatile("s_waitcnt vmcnt(4)" ::: "memory");   // K(kt),V(kt),Q landed
    {
      union { int4 v; unsigned short u[8]; } lo, hi;
      lo.v = vlo; hi.v = vhi;
#pragma unroll
      for (int j = 0; j < 8; ++j) Vt[cur][(dc + j) * 32 + colv] = lo.u[j];
#pragma unroll
      for (int j = 0; j < 8; ++j) Vt[cur][(dc + 8 + j) * 32 + colv] = hi.u[j];
    }
    asm volatile("s_waitcnt lgkmcnt(0)" ::: "memory");
    __builtin_amdgcn_sched_barrier(0);
    __builtin_amdgcn_s_barrier();                       // B1: Vt[cur] ready, Ks[cur] landed
    __builtin_amdgcn_sched_barrier(0);

    f32x4_t sa0 = (f32x4_t)0.f, sa1 = (f32x4_t)0.f;
    const int arow = q0 + (lane & 15);
    const int kr0 = lane & 15, kr1 = 16 + (lane & 15);
#pragma unroll
    for (int ks = 0; ks < 4; ++ks) {
      const bf16x8_t aq  = *(const bf16x8_t*)&Qs[(arow * 128 + ks * 32 + (lane >> 4) * 8) ^ ((arow & 7) << 3)];
      const bf16x8_t bk0 = *(const bf16x8_t*)&Ks[cur][(kr0 * 128 + ks * 32 + (lane >> 4) * 8) ^ ((kr0 & 7) << 3)];
      sa0 = __builtin_amdgcn_mfma_f32_16x16x32_bf16(aq, bk0, sa0, 0, 0, 0);
      const bf16x8_t bk1 = *(const bf16x8_t*)&Ks[cur][(kr1 * 128 + ks * 32 + (lane >> 4) * 8) ^ ((kr1 & 7) << 3)];
      sa1 = __builtin_amdgcn_mfma_f32_16x16x32_bf16(aq, bk1, sa1, 0, 0, 0);
    }
    float pm[4];
#pragma unroll
    for (int r = 0; r < 4; ++r) {
      float v = fmaxf(sa0[r], sa1[r]) * rs;
#pragma unroll
      for (int off = 1; off < 16; off <<= 1) v = fmaxf(v, __shfl_xor(v, off, 64));
      pm[r] = v;
    }
    float corr[4], mnew[4];
#pragma unroll
    for (int r = 0; r < 4; ++r) {
      mnew[r] = fmaxf(mrun[r], pm[r]);
      corr[r] = __expf(mrun[r] - mnew[r]);
      mrun[r] = mnew[r];
    }
    float pv0[4], pv1[4];
#pragma unroll
    for (int r = 0; r < 4; ++r) {
      pv0[r] = __expf(sa0[r] * rs - mnew[r]);
      pv1[r] = __expf(sa1[r] * rs - mnew[r]);
    }
#pragma unroll
    for (int r = 0; r < 4; ++r) {
      float v = pv0[r] + pv1[r];
#pragma unroll
      for (int off = 1; off < 16; off <<= 1) v += __shfl_xor(v, off, 64);
      lrun[r] = lrun[r] * corr[r] + v;
    }
#pragma unroll
    for (int i = 0; i < 8; ++i)
#pragma unroll
      for (int r = 0; r < 4; ++r) oa[i][r] *= corr[r];

#pragma unroll
    for (int r = 0; r < 4; ++r) {
      Ps[wid * 512 + ((lane >> 4) * 4 + r) * 32 + (lane & 15)]      = f2b(pv0[r]);
      Ps[wid * 512 + ((lane >> 4) * 4 + r) * 32 + 16 + (lane & 15)] = f2b(pv1[r]);
    }
    const bf16x8_t pf = *(const bf16x8_t*)&Ps[wid * 512 + (lane & 15) * 32 + (lane >> 4) * 8];

#pragma unroll
    for (int nt2 = 0; nt2 < 8; ++nt2) {
      const bf16x8_t vf = *(const bf16x8_t*)&Vt[cur][(nt2 * 16 + (lane & 15)) * 32 + (((lane >> 4) ^ (nt2 & 3)) << 3)];
      oa[nt2] = __builtin_amdgcn_mfma_f32_16x16x32_bf16(pf, vf, oa[nt2], 0, 0, 0);
    }
    __builtin_amdgcn_s_barrier();                       // B2: all waves done with Ks/Vt[cur]
    __builtin_amdgcn_sched_barrier(0);
    if (kt + 2 < SEQ / 32) { stK(kt + 2, cur); ldV(kt + 2, vlo, vhi); }
  };

  for (int kt2 = 0; kt2 < SEQ / 32; kt2 += 2) {
    iter(kt2,     0, vlo0, vhi0);
    iter(kt2 + 1, 1, vlo1, vhi1);
  }

  float inv[4];
#pragma unroll
  for (int r = 0; r < 4; ++r) inv[r] = 1.f / lrun[r];
#pragma unroll
  for (int nt2 = 0; nt2 < 8; ++nt2) {
    const int col = h * HD + nt2 * 16 + (lane & 15);
#pragma unroll
    for (int r = 0; r < 4; ++r) {
      const int row = qt * 64 + q0 + (lane >> 4) * 4 + r;
      O[(size_t)(b * SEQ + row) * DIM + col] = f2b(oa[nt2][r] * inv[r]);
    }
  }
}

// ---------------- launch ----------------
extern "C" void kernel_launch(void* const* d_in, const int* in_sizes, int n_in,
                              void* d_out, int out_size, void* d_ws, size_t ws_size,
                              hipStream_t stream)
{
  (void)in_sizes; (void)n_in; (void)out_size; (void)ws_size;
  const float* x   = (const float*)d_in[0];
  const float* fr  = (const float*)d_in[1];
  const float* ga  = (const float*)d_in[3];
  const float* gf  = (const float*)d_in[4];
  const float* wq  = (const float*)d_in[5];
  const float* wqb = (const float*)d_in[6];
  const float* wk  = (const float*)d_in[7];
  const float* wkb = (const float*)d_in[8];
  const float* wv  = (const float*)d_in[9];
  const float* wvb = (const float*)d_in[10];
  const float* wo  = (const float*)d_in[11];
  const float* wob = (const float*)d_in[12];
  const float* w1  = (const float*)d_in[13];
  const float* w3  = (const float*)d_in[14];
  const float* w2  = (const float*)d_in[15];
  float* out = (float*)d_out;

  constexpr size_t MB = 1ull << 20;
  char* ws = (char*)d_ws;
  unsigned short* xn = (unsigned short*)(ws);              // [0,64) MiB
  unsigned short* qb = (unsigned short*)(ws + 64*MB);      // [64,128)
  unsigned short* kb = (unsigned short*)(ws + 128*MB);     // [128,144)
  unsigned short* vb = (unsigned short*)(ws + 144*MB);     // [144,160)
  unsigned short* ao = (unsigned short*)(ws + 160*MB);     // [160,224)
  unsigned short* hn = (unsigned short*)(ws + 224*MB);     // [224,288)
  unsigned short* g  = (unsigned short*)(ws);              // [0,172) alias (dead by FFN time)
  unsigned short* wscr = (unsigned short*)(ws + 288*MB);   // JIT bf16 weights
  unsigned short* wqB = wscr;                               // 32 MiB
  unsigned short* wkB = wscr + 16*MB;                       // 8 MiB
  unsigned short* wvB = wscr + 20*MB;                       // 8 MiB
  unsigned short* woB = wscr;                               // 32 MiB (after QKV)
  unsigned short* w1B = wscr;                               // 90 MiB
  unsigned short* w3B = wscr + 45*MB;                       // 90 MiB
  unsigned short* w2B = wscr;                               // 90 MiB

  rmsnorm_k<<<MTOT, 256, 0, stream>>>(x, ga, xn);
  cvt_bf16_k<<<(NH*HD*DIM)/2048,  256, 0, stream>>>(wq, wqB);
  cvt_bf16_k<<<(NKV*HD*DIM)/2048, 256, 0, stream>>>(wk, wkB);
  cvt_bf16_k<<<(NKV*HD*DIM)/2048, 256, 0, stream>>>(wv, wvB);
  gemm256<0><<<(MTOT/256)*((DIM+2*NKV*HD)/256), 512, 0, stream>>>(
      xn, wqB, nullptr, wqb, nullptr, nullptr, qb,
      wkB, wvB, wkb, wvb, kb, vb, DIM);
  rope_k<NH><<<(MTOT*NH*16)/256,  256, 0, stream>>>(qb, fr);
  rope_k<NKV><<<(MTOT*NKV*16)/256,256, 0, stream>>>(kb, fr);
  attn_k<<<BATCH*NH*(SEQ/64), 256, 0, stream>>>(qb, kb, vb, ao);
  cvt_bf16_k<<<(DIM*DIM)/2048, 256, 0, stream>>>(wo, woB);
  gemm256<1><<<(MTOT/256)*(DIM/256), 512, 0, stream>>>(
      ao, woB, nullptr, wob, x, out, nullptr,
      nullptr, nullptr, nullptr, nullptr, nullptr, nullptr, DIM);
  rmsnorm_k<<<MTOT, 256, 0, stream>>>(out, gf, hn);
  cvt_bf16_k<<<(FFNH*DIM)/2048, 256, 0, stream>>>(w1, w1B);
  cvt_bf16_k<<<(FFNH*DIM)/2048, 256, 0, stream>>>(w3, w3B);
  gemm256<3><<<(MTOT/256)*(FFNH/128), 512, 0, stream>>>(
      hn, w1B, w3B, nullptr, nullptr, nullptr, g,
      nullptr, nullptr, nullptr, nullptr, nullptr, nullptr, DIM);
  cvt_bf16_k<<<(FFNH*DIM)/2048, 256, 0, stream>>>(w2, w2B);
  gemm256<2><<<(MTOT/256)*(DIM/256), 512, 0, stream>>>(
      g, w2B, nullptr, nullptr, out, out, nullptr,
      nullptr, nullptr, nullptr, nullptr, nullptr, nullptr, FFNH);
}

// Round 5
// 4028.799 us; speedup vs baseline: 1.8199x; 1.0417x over previous
//
#include <hip/hip_runtime.h>
#include <hip/hip_bf16.h>

#define DIM   4096
#define NH    32
#define NKV   8
#define HD    128
#define FFNH  11008
#define BATCH 4
#define SEQ   2048
#define MTOT  (BATCH*SEQ)   // 8192

using bf16x8_t = __attribute__((ext_vector_type(8))) short;
using f32x4_t  = __attribute__((ext_vector_type(4))) float;

typedef const __attribute__((address_space(1))) unsigned int GlbU32;
typedef __attribute__((address_space(3))) unsigned int LdsU32;

__device__ __forceinline__ unsigned short f2b(float f) {
  union { float f; unsigned int u; } v; v.f = f;
  return (unsigned short)((v.u + 0x7fffu + ((v.u >> 16) & 1u)) >> 16);
}
__device__ __forceinline__ float b2f(unsigned short b) {
  union { unsigned int u; float f; } v; v.u = ((unsigned int)b) << 16;
  return v.f;
}
__device__ __forceinline__ void gll16(const void* g, void* l) {
  __builtin_amdgcn_global_load_lds((GlbU32*)g, (LdsU32*)l, 16, 0, 0);
}

#define VM8  asm volatile("s_waitcnt vmcnt(8)" ::: "memory")
#define VM4M asm volatile("s_waitcnt vmcnt(4)" ::: "memory")
#define VM0  asm volatile("s_waitcnt vmcnt(0)" ::: "memory")

// ---------------- fp32 -> bf16 bulk convert ----------------
__global__ __launch_bounds__(256)
void cvt_bf16_k(const float* __restrict__ src, unsigned short* __restrict__ dst)
{
  const size_t i = ((size_t)blockIdx.x * 256 + threadIdx.x) * 8;
  const float4 a = *(const float4*)&src[i];
  const float4 b = *(const float4*)&src[i + 4];
  union { int4 v; unsigned short u[8]; } o;
  o.u[0] = f2b(a.x); o.u[1] = f2b(a.y); o.u[2] = f2b(a.z); o.u[3] = f2b(a.w);
  o.u[4] = f2b(b.x); o.u[5] = f2b(b.y); o.u[6] = f2b(b.z); o.u[7] = f2b(b.w);
  *(int4*)&dst[i] = o.v;
}

// ---------------- RMSNorm: fp32 in -> bf16 out ----------------
__global__ __launch_bounds__(256)
void rmsnorm_k(const float* __restrict__ X, const float* __restrict__ gamma,
               unsigned short* __restrict__ Y)
{
  const int row = blockIdx.x, t = threadIdx.x;
  const float* xr = X + (size_t)row * DIM;
  float4 v[4];
  float ss = 0.f;
#pragma unroll
  for (int p = 0; p < 4; ++p) {
    v[p] = *(const float4*)&xr[p * 1024 + t * 4];
    ss += v[p].x*v[p].x + v[p].y*v[p].y + v[p].z*v[p].z + v[p].w*v[p].w;
  }
#pragma unroll
  for (int off = 32; off >= 1; off >>= 1) ss += __shfl_xor(ss, off, 64);
  __shared__ float red[4];
  if ((t & 63) == 0) red[t >> 6] = ss;
  __syncthreads();
  const float tot = red[0] + red[1] + red[2] + red[3];
  const float rn = rsqrtf(tot * (1.f / DIM) + 1e-6f);
  unsigned short* yr = Y + (size_t)row * DIM;
#pragma unroll
  for (int p = 0; p < 4; ++p) {
    const float4 gv = *(const float4*)&gamma[p * 1024 + t * 4];
    short4 o;
    o.x = (short)f2b(v[p].x * gv.x * rn);
    o.y = (short)f2b(v[p].y * gv.y * rn);
    o.z = (short)f2b(v[p].z * gv.z * rn);
    o.w = (short)f2b(v[p].w * gv.w * rn);
    *(short4*)&yr[p * 1024 + t * 4] = o;
  }
}

// ---------------- RoPE in-place on bf16 [rows][NHT*128] ----------------
template<int NHT>
__global__ __launch_bounds__(256)
void rope_k(unsigned short* __restrict__ buf, const float* __restrict__ fr)
{
  const int u = blockIdx.x * 256 + threadIdx.x;
  const int per_row = NHT * 16;
  const int row  = u / per_row;
  const int rem  = u - row * per_row;
  const int head = rem >> 4;
  const int i4   = (rem & 15) << 2;
  const int s    = row & (SEQ - 1);
  unsigned short* p = buf + (size_t)row * (NHT * HD) + head * HD + i4 * 2;
  union { int4 v; unsigned short u16[8]; } d;
  d.v = *(const int4*)p;
  const float4 f = *(const float4*)&fr[s * 64 + i4];
  const float fa[4] = {f.x, f.y, f.z, f.w};
#pragma unroll
  for (int i = 0; i < 4; ++i) {
    float sn, c;
    __sincosf(fa[i], &sn, &c);
    const float x0 = b2f(d.u16[2*i]), x1 = b2f(d.u16[2*i+1]);
    d.u16[2*i]   = f2b(x0 * c - x1 * sn);
    d.u16[2*i+1] = f2b(x0 * sn + x1 * c);
  }
  *(int4*)p = d.v;
}

// ======================= 256x256 8-phase GEMM =======================
// Work order (all modes): XCD-chunk -> (tm_group of 8) x (tn) x (tm_in).
// A-strip (16 MB) stays L3-resident while the weight panel streams; the 4
// concurrent tm-groups (XCD pairs) scan the same tn panels in lock-step, so
// weights are HBM-fetched ~once.
// MODE 0: QKV fused (+bias -> bf16); 1: O-proj (+bias+res -> f32);
// MODE 2: W2 (+res -> f32); 3: W13 fused SwiGLU (-> bf16).
#define GP0(SLOT, STG, VM) {                                              \
  _Pragma("unroll") for (int n_ = 0; n_ < 4; ++n_) bf[n_] = rdB((SLOT), n_); \
  _Pragma("unroll") for (int m_ = 0; m_ < 4; ++m_) af[m_] = rdA((SLOT), m_ * 16); \
  STG;                                                                    \
  __builtin_amdgcn_s_barrier();                                           \
  asm volatile("s_waitcnt lgkmcnt(0)" ::: "memory");                      \
  __builtin_amdgcn_sched_barrier(0);                                      \
  __builtin_amdgcn_s_setprio(1);                                          \
  _Pragma("unroll") for (int m_ = 0; m_ < 4; ++m_)                        \
    _Pragma("unroll") for (int n_ = 0; n_ < 4; ++n_)                      \
      acc[m_][n_] = __builtin_amdgcn_mfma_f32_16x16x32_bf16(af[m_], bf[n_], acc[m_][n_], 0, 0, 0); \
  __builtin_amdgcn_s_setprio(0);                                          \
  VM;                                                                     \
  __builtin_amdgcn_s_barrier();                                           \
  __builtin_amdgcn_sched_barrier(0);                                      \
}
#define GP1(SLOT, STG, VM) {                                              \
  _Pragma("unroll") for (int m_ = 0; m_ < 4; ++m_) af[m_] = rdA((SLOT), 64 + m_ * 16); \
  STG;                                                                    \
  __builtin_amdgcn_s_barrier();                                           \
  asm volatile("s_waitcnt lgkmcnt(0)" ::: "memory");                      \
  __builtin_amdgcn_sched_barrier(0);                                      \
  __builtin_amdgcn_s_setprio(1);                                          \
  _Pragma("unroll") for (int m_ = 0; m_ < 4; ++m_)                        \
    _Pragma("unroll") for (int n_ = 0; n_ < 4; ++n_)                      \
      acc[4 + m_][n_] = __builtin_amdgcn_mfma_f32_16x16x32_bf16(af[m_], bf[n_], acc[4 + m_][n_], 0, 0, 0); \
  __builtin_amdgcn_s_setprio(0);                                          \
  VM;                                                                     \
  __builtin_amdgcn_s_barrier();                                           \
  __builtin_amdgcn_sched_barrier(0);                                      \
}

template<int MODE>
__global__ __launch_bounds__(512)
void gemm256(const unsigned short* __restrict__ A,
             const unsigned short* __restrict__ W,
             const unsigned short* __restrict__ W3p,
             const float* __restrict__ bias,
             const float* res,
             float* outF,
             unsigned short* __restrict__ outH,
             const unsigned short* __restrict__ wkp,
             const unsigned short* __restrict__ wvp,
             const float* __restrict__ bkp,
             const float* __restrict__ bvp,
             unsigned short* __restrict__ okp,
             unsigned short* __restrict__ ovp,
             int K)
{
  __shared__ __align__(16) char smem[131072];
  const int t = threadIdx.x, lane = t & 63, wid = t >> 6;
  const int wr = wid >> 2, wc = wid & 3;
  const int G = gridDim.x, bid = blockIdx.x;
  const int wg = (bid & 7) * (G >> 3) + (bid >> 3);   // XCD-chunked
  const int NBN = G >> 5;                             // NBM = 32 (M = 8192)
  const int span = NBN << 3;                          // TMG = 8
  const int tmg = wg / span, rr = wg - tmg * span;
  const int tn = rr >> 3, tm = (tmg << 3) + (rr & 7);
  const int m0 = tm << 8;
  const int NT = K >> 6, NSUB = K >> 5;

  const unsigned short *P1, *P2;
  const float* bp = bias;
  unsigned short* oh = outH;
  int nloc = 0, colsN = 4096;
  if constexpr (MODE == 0) {
    const int n0 = tn << 8;
    if (n0 < 4096)      { nloc = n0;        P1 = W   + (size_t)nloc * K; bp = bias; oh = outH; colsN = 4096; }
    else if (n0 < 5120) { nloc = n0 - 4096; P1 = wkp + (size_t)nloc * K; bp = bkp;  oh = okp;  colsN = 1024; }
    else                { nloc = n0 - 5120; P1 = wvp + (size_t)nloc * K; bp = bvp;  oh = ovp;  colsN = 1024; }
    P2 = P1 + (size_t)128 * K;
  } else if constexpr (MODE == 3) {
    const int n0w = tn << 7;
    P1 = W   + (size_t)n0w * K;
    P2 = W3p + (size_t)n0w * K;
    nloc = n0w;
  } else {
    const int n0 = tn << 8;
    P1 = W + (size_t)n0 * K;
    P2 = P1 + (size_t)128 * K;
    nloc = n0;
  }

  const int r0 = t >> 2, gg = t & 3;
  const int gsw = gg ^ ((r0 >> 1) & 3);

  auto stA = [&](int sig) {
    if (sig < NSUB) {
      const int slot = sig & 3;
      gll16(A + (size_t)(m0 + r0) * K + sig * 32 + gsw * 8,
            smem + slot * 16384 + wid * 1024);
      gll16(A + (size_t)(m0 + 128 + r0) * K + sig * 32 + gsw * 8,
            smem + slot * 16384 + 8192 + wid * 1024);
    }
  };
  auto stB = [&](int sig) {
    if (sig < NSUB) {
      const int slot = sig & 3;
      gll16(P1 + (size_t)r0 * K + sig * 32 + gsw * 8,
            smem + 65536 + slot * 16384 + wid * 1024);
      gll16(P2 + (size_t)r0 * K + sig * 32 + gsw * 8,
            smem + 65536 + slot * 16384 + 8192 + wid * 1024);
    }
  };
  auto rdA = [&](int slot, int mo) -> bf16x8_t {
    const int lrow = wr * 128 + mo + (lane & 15);
    const int g = (lane >> 4) ^ ((lrow >> 1) & 3);
    return *(const bf16x8_t*)(smem + slot * 16384 + lrow * 64 + g * 16);
  };
  auto rdB = [&](int slot, int nf) -> bf16x8_t {
    const int brow = wc * 64 + nf * 16 + (lane & 15);
    const int g = (lane >> 4) ^ ((brow >> 1) & 3);
    return *(const bf16x8_t*)(smem + 65536 + slot * 16384 + brow * 64 + g * 16);
  };

  f32x4_t acc[8][4];
#pragma unroll
  for (int i = 0; i < 8; ++i)
#pragma unroll
    for (int j = 0; j < 4; ++j) acc[i][j] = (f32x4_t)0.f;
  bf16x8_t af[4], bf[4];

  stA(0); stB(0); stA(1); stB(1); stA(2); stB(2);
  VM8;
  __builtin_amdgcn_s_barrier();
  __builtin_amdgcn_sched_barrier(0);

  for (int kt = 0; kt < NT; ++kt) {
    const int slot0 = (2 * kt) & 3;
    const int slot1 = slot0 + 1;
    GP0(slot0, stA(2 * kt + 3), (void)0);
    GP1(slot0, stB(2 * kt + 3), if (kt < NT - 1) { VM8; } else { VM0; });
    GP0(slot1, stA(2 * kt + 4), (void)0);
    GP1(slot1, stB(2 * kt + 4), if (kt < NT - 2) { VM8; } else { VM4M; });
  }

  if constexpr (MODE == 0) {
#pragma unroll
    for (int ni = 0; ni < 4; ++ni) {
      const int col = nloc + wc * 64 + ni * 16 + (lane & 15);
      const float bv = bp[col];
#pragma unroll
      for (int mi = 0; mi < 8; ++mi)
#pragma unroll
        for (int r = 0; r < 4; ++r) {
          const int row = m0 + wr * 128 + mi * 16 + (lane >> 4) * 4 + r;
          oh[(size_t)row * colsN + col] = f2b(acc[mi][ni][r] + bv);
        }
    }
  } else if constexpr (MODE == 1 || MODE == 2) {
#pragma unroll
    for (int ni = 0; ni < 4; ++ni) {
      const int col = nloc + wc * 64 + ni * 16 + (lane & 15);
      float bv = 0.f;
      if constexpr (MODE == 1) bv = bias[col];
#pragma unroll
      for (int mi = 0; mi < 8; ++mi)
#pragma unroll
        for (int r = 0; r < 4; ++r) {
          const int row = m0 + wr * 128 + mi * 16 + (lane >> 4) * 4 + r;
          const size_t idx = (size_t)row * 4096 + col;
          outF[idx] = acc[mi][ni][r] + bv + res[idx];
        }
    }
  } else {
    if (wc >= 2) {
      const int widx = wr * 2 + (wc - 2);
#pragma unroll
      for (int ni = 0; ni < 4; ++ni)
#pragma unroll
        for (int mi = 0; mi < 8; ++mi)
#pragma unroll
          for (int r = 0; r < 4; ++r) {
            const int lrow = mi * 16 + (lane >> 4) * 4 + r;
            const int ncol = ni * 16 + (lane & 15);
            *(unsigned short*)(smem + widx * 16384 + lrow * 128 + ncol * 2) =
                f2b(acc[mi][ni][r]);
          }
    }
    __syncthreads();
    if (wc < 2) {
      const int widx = wr * 2 + wc;
#pragma unroll
      for (int ni = 0; ni < 4; ++ni)
#pragma unroll
        for (int mi = 0; mi < 8; ++mi)
#pragma unroll
          for (int r = 0; r < 4; ++r) {
            const int lrow = mi * 16 + (lane >> 4) * 4 + r;
            const int ncol = ni * 16 + (lane & 15);
            const float s3 = b2f(*(const unsigned short*)(smem + widx * 16384 + lrow * 128 + ncol * 2));
            const float s1 = acc[mi][ni][r];
            const float sig = 1.f / (1.f + __expf(-s1));
            const int row = m0 + wr * 128 + lrow;
            outH[(size_t)row * FFNH + nloc + wc * 64 + ncol] = f2b(s1 * sig * s3);
          }
    }
  }
}

// ---------------- Flash attention (non-causal, GQA 4:1) ----------------
__global__ __launch_bounds__(256)
void attn_k(const unsigned short* __restrict__ Q, const unsigned short* __restrict__ Kb,
            const unsigned short* __restrict__ Vb, unsigned short* __restrict__ O)
{
  __shared__ unsigned short Qs[8192];
  __shared__ unsigned short Ks[2][4096];
  __shared__ unsigned short Vt[2][4096];
  __shared__ unsigned short Ps[2048];
  const int t = threadIdx.x, lane = t & 63, wid = t >> 6;
  const int bx = blockIdx.x;
  const int qt = bx & 31, h = (bx >> 5) & 31, b = bx >> 10;
  const int kvh = h >> 2;
  const float rs = 0.08838834764831845f;

#pragma unroll
  for (int oo = 0; oo < 4; ++oo) {
    const int o = wid * 4 + oo;
    const int row = o * 4 + (lane >> 4);
    const int gl  = (lane & 15) ^ (row & 7);
    gll16(Q + (size_t)(b * SEQ + qt * 64 + row) * DIM + h * HD + gl * 8, &Qs[o * 512]);
  }

  const unsigned short* Kbase = Kb + (size_t)(b * SEQ) * (NKV * HD) + kvh * HD;
  const unsigned short* Vbase = Vb + (size_t)(b * SEQ) * (NKV * HD) + kvh * HD;

  auto stK = [&](int kt, int slot) {
#pragma unroll
    for (int oo = 0; oo < 2; ++oo) {
      const int o = wid * 2 + oo;
      const int row = o * 4 + (lane >> 4);
      const int gl  = (lane & 15) ^ (row & 7);
      gll16(Kbase + (size_t)(kt * 32 + row) * (NKV * HD) + gl * 8, &Ks[slot][o * 512]);
    }
  };
  const int kv = t >> 3, dc = (t & 7) << 4;
  const int colv = kv ^ ((t & 3) << 3);
  auto ldV = [&](int kt, int4& lo, int4& hi) {
    const unsigned short* gp = Vbase + (size_t)(kt * 32 + kv) * (NKV * HD) + dc;
    lo = *(const int4*)gp;
    hi = *(const int4*)(gp + 8);
  };

  int4 vlo0, vhi0, vlo1, vhi1;
  stK(0, 0); ldV(0, vlo0, vhi0);
  stK(1, 1); ldV(1, vlo1, vhi1);

  f32x4_t oa[8];
#pragma unroll
  for (int i = 0; i < 8; ++i) oa[i] = (f32x4_t)0.f;
  float mrun[4] = {-1e30f, -1e30f, -1e30f, -1e30f};
  float lrun[4] = {0.f, 0.f, 0.f, 0.f};
  const int q0 = wid * 16;

  auto iter = [&](int kt, int cur, int4& vlo, int4& vhi) {
    asm volatile("s_waitcnt vmcnt(4)" ::: "memory");
    {
      union { int4 v; unsigned short u[8]; } lo, hi;
      lo.v = vlo; hi.v = vhi;
#pragma unroll
      for (int j = 0; j < 8; ++j) Vt[cur][(dc + j) * 32 + colv] = lo.u[j];
#pragma unroll
      for (int j = 0; j < 8; ++j) Vt[cur][(dc + 8 + j) * 32 + colv] = hi.u[j];
    }
    asm volatile("s_waitcnt lgkmcnt(0)" ::: "memory");
    __builtin_amdgcn_sched_barrier(0);
    __builtin_amdgcn_s_barrier();
    __builtin_amdgcn_sched_barrier(0);

    f32x4_t sa0 = (f32x4_t)0.f, sa1 = (f32x4_t)0.f;
    const int arow = q0 + (lane & 15);
    const int kr0 = lane & 15, kr1 = 16 + (lane & 15);
#pragma unroll
    for (int ks = 0; ks < 4; ++ks) {
      const bf16x8_t aq  = *(const bf16x8_t*)&Qs[(arow * 128 + ks * 32 + (lane >> 4) * 8) ^ ((arow & 7) << 3)];
      const bf16x8_t bk0 = *(const bf16x8_t*)&Ks[cur][(kr0 * 128 + ks * 32 + (lane >> 4) * 8) ^ ((kr0 & 7) << 3)];
      sa0 = __builtin_amdgcn_mfma_f32_16x16x32_bf16(aq, bk0, sa0, 0, 0, 0);
      const bf16x8_t bk1 = *(const bf16x8_t*)&Ks[cur][(kr1 * 128 + ks * 32 + (lane >> 4) * 8) ^ ((kr1 & 7) << 3)];
      sa1 = __builtin_amdgcn_mfma_f32_16x16x32_bf16(aq, bk1, sa1, 0, 0, 0);
    }
    float pm[4];
#pragma unroll
    for (int r = 0; r < 4; ++r) {
      float v = fmaxf(sa0[r], sa1[r]) * rs;
#pragma unroll
      for (int off = 1; off < 16; off <<= 1) v = fmaxf(v, __shfl_xor(v, off, 64));
      pm[r] = v;
    }
    float corr[4], mnew[4];
#pragma unroll
    for (int r = 0; r < 4; ++r) {
      mnew[r] = fmaxf(mrun[r], pm[r]);
      corr[r] = __expf(mrun[r] - mnew[r]);
      mrun[r] = mnew[r];
    }
    float pv0[4], pv1[4];
#pragma unroll
    for (int r = 0; r < 4; ++r) {
      pv0[r] = __expf(sa0[r] * rs - mnew[r]);
      pv1[r] = __expf(sa1[r] * rs - mnew[r]);
    }
#pragma unroll
    for (int r = 0; r < 4; ++r) {
      float v = pv0[r] + pv1[r];
#pragma unroll
      for (int off = 1; off < 16; off <<= 1) v += __shfl_xor(v, off, 64);
      lrun[r] = lrun[r] * corr[r] + v;
    }
#pragma unroll
    for (int i = 0; i < 8; ++i)
#pragma unroll
      for (int r = 0; r < 4; ++r) oa[i][r] *= corr[r];

#pragma unroll
    for (int r = 0; r < 4; ++r) {
      Ps[wid * 512 + ((lane >> 4) * 4 + r) * 32 + (lane & 15)]      = f2b(pv0[r]);
      Ps[wid * 512 + ((lane >> 4) * 4 + r) * 32 + 16 + (lane & 15)] = f2b(pv1[r]);
    }
    const bf16x8_t pf = *(const bf16x8_t*)&Ps[wid * 512 + (lane & 15) * 32 + (lane >> 4) * 8];

#pragma unroll
    for (int nt2 = 0; nt2 < 8; ++nt2) {
      const bf16x8_t vf = *(const bf16x8_t*)&Vt[cur][(nt2 * 16 + (lane & 15)) * 32 + (((lane >> 4) ^ (nt2 & 3)) << 3)];
      oa[nt2] = __builtin_amdgcn_mfma_f32_16x16x32_bf16(pf, vf, oa[nt2], 0, 0, 0);
    }
    __builtin_amdgcn_s_barrier();
    __builtin_amdgcn_sched_barrier(0);
    if (kt + 2 < SEQ / 32) { stK(kt + 2, cur); ldV(kt + 2, vlo, vhi); }
  };

  for (int kt2 = 0; kt2 < SEQ / 32; kt2 += 2) {
    iter(kt2,     0, vlo0, vhi0);
    iter(kt2 + 1, 1, vlo1, vhi1);
  }

  float inv[4];
#pragma unroll
  for (int r = 0; r < 4; ++r) inv[r] = 1.f / lrun[r];
#pragma unroll
  for (int nt2 = 0; nt2 < 8; ++nt2) {
    const int col = h * HD + nt2 * 16 + (lane & 15);
#pragma unroll
    for (int r = 0; r < 4; ++r) {
      const int row = qt * 64 + q0 + (lane >> 4) * 4 + r;
      O[(size_t)(b * SEQ + row) * DIM + col] = f2b(oa[nt2][r] * inv[r]);
    }
  }
}

// ---------------- launch ----------------
extern "C" void kernel_launch(void* const* d_in, const int* in_sizes, int n_in,
                              void* d_out, int out_size, void* d_ws, size_t ws_size,
                              hipStream_t stream)
{
  (void)in_sizes; (void)n_in; (void)out_size; (void)ws_size;
  const float* x   = (const float*)d_in[0];
  const float* fr  = (const float*)d_in[1];
  const float* ga  = (const float*)d_in[3];
  const float* gf  = (const float*)d_in[4];
  const float* wq  = (const float*)d_in[5];
  const float* wqb = (const float*)d_in[6];
  const float* wk  = (const float*)d_in[7];
  const float* wkb = (const float*)d_in[8];
  const float* wv  = (const float*)d_in[9];
  const float* wvb = (const float*)d_in[10];
  const float* wo  = (const float*)d_in[11];
  const float* wob = (const float*)d_in[12];
  const float* w1  = (const float*)d_in[13];
  const float* w3  = (const float*)d_in[14];
  const float* w2  = (const float*)d_in[15];
  float* out = (float*)d_out;

  constexpr size_t MB = 1ull << 20;
  char* ws = (char*)d_ws;
  unsigned short* xn = (unsigned short*)(ws);              // [0,64) MiB
  unsigned short* qb = (unsigned short*)(ws + 64*MB);      // [64,128)
  unsigned short* kb = (unsigned short*)(ws + 128*MB);     // [128,144)
  unsigned short* vb = (unsigned short*)(ws + 144*MB);     // [144,160)
  unsigned short* ao = (unsigned short*)(ws + 160*MB);     // [160,224)
  unsigned short* hn = (unsigned short*)(ws + 224*MB);     // [224,288)
  unsigned short* g  = (unsigned short*)(ws);              // [0,172) alias (dead by FFN time)
  unsigned short* wscr = (unsigned short*)(ws + 288*MB);   // JIT bf16 weights
  unsigned short* wqB = wscr;                               // 32 MiB
  unsigned short* wkB = wscr + 16*MB;                       // 8 MiB
  unsigned short* wvB = wscr + 20*MB;                       // 8 MiB
  unsigned short* woB = wscr;                               // 32 MiB (after QKV)
  unsigned short* w1B = wscr;                               // 90 MiB
  unsigned short* w3B = wscr + 45*MB;                       // 90 MiB
  unsigned short* w2B = wscr;                               // 90 MiB

  rmsnorm_k<<<MTOT, 256, 0, stream>>>(x, ga, xn);
  cvt_bf16_k<<<(NH*HD*DIM)/2048,  256, 0, stream>>>(wq, wqB);
  cvt_bf16_k<<<(NKV*HD*DIM)/2048, 256, 0, stream>>>(wk, wkB);
  cvt_bf16_k<<<(NKV*HD*DIM)/2048, 256, 0, stream>>>(wv, wvB);
  gemm256<0><<<(MTOT/256)*((DIM+2*NKV*HD)/256), 512, 0, stream>>>(
      xn, wqB, nullptr, wqb, nullptr, nullptr, qb,
      wkB, wvB, wkb, wvb, kb, vb, DIM);
  rope_k<NH><<<(MTOT*NH*16)/256,  256, 0, stream>>>(qb, fr);
  rope_k<NKV><<<(MTOT*NKV*16)/256,256, 0, stream>>>(kb, fr);
  attn_k<<<BATCH*NH*(SEQ/64), 256, 0, stream>>>(qb, kb, vb, ao);
  cvt_bf16_k<<<(DIM*DIM)/2048, 256, 0, stream>>>(wo, woB);
  gemm256<1><<<(MTOT/256)*(DIM/256), 512, 0, stream>>>(
      ao, woB, nullptr, wob, x, out, nullptr,
      nullptr, nullptr, nullptr, nullptr, nullptr, nullptr, DIM);
  rmsnorm_k<<<MTOT, 256, 0, stream>>>(out, gf, hn);
  cvt_bf16_k<<<(FFNH*DIM)/2048, 256, 0, stream>>>(w1, w1B);
  cvt_bf16_k<<<(FFNH*DIM)/2048, 256, 0, stream>>>(w3, w3B);
  gemm256<3><<<(MTOT/256)*(FFNH/128), 512, 0, stream>>>(
      hn, w1B, w3B, nullptr, nullptr, nullptr, g,
      nullptr, nullptr, nullptr, nullptr, nullptr, nullptr, DIM);
  cvt_bf16_k<<<(FFNH*DIM)/2048, 256, 0, stream>>>(w2, w2B);
  gemm256<2><<<(MTOT/256)*(DIM/256), 512, 0, stream>>>(
      g, w2B, nullptr, nullptr, out, out, nullptr,
      nullptr, nullptr, nullptr, nullptr, nullptr, nullptr, FFNH);
}

// Round 6
// 3820.527 us; speedup vs baseline: 1.9191x; 1.0545x over previous
//
#include <hip/hip_runtime.h>
#include <hip/hip_bf16.h>

#define DIM   4096
#define NH    32
#define NKV   8
#define HD    128
#define FFNH  11008
#define BATCH 4
#define SEQ   2048
#define MTOT  (BATCH*SEQ)   // 8192

using bf16x8_t = __attribute__((ext_vector_type(8))) short;
using f32x4_t  = __attribute__((ext_vector_type(4))) float;

typedef const __attribute__((address_space(1))) unsigned int GlbU32;
typedef __attribute__((address_space(3))) unsigned int LdsU32;

__device__ __forceinline__ unsigned short f2b(float f) {
  union { float f; unsigned int u; } v; v.f = f;
  return (unsigned short)((v.u + 0x7fffu + ((v.u >> 16) & 1u)) >> 16);
}
__device__ __forceinline__ float b2f(unsigned short b) {
  union { unsigned int u; float f; } v; v.u = ((unsigned int)b) << 16;
  return v.f;
}
__device__ __forceinline__ void gll16(const void* g, void* l) {
  __builtin_amdgcn_global_load_lds((GlbU32*)g, (LdsU32*)l, 16, 0, 0);
}

#define VM8  asm volatile("s_waitcnt vmcnt(8)" ::: "memory")
#define VM4M asm volatile("s_waitcnt vmcnt(4)" ::: "memory")
#define VM0  asm volatile("s_waitcnt vmcnt(0)" ::: "memory")

// ---------------- fp32 -> bf16 bulk convert ----------------
__global__ __launch_bounds__(256)
void cvt_bf16_k(const float* __restrict__ src, unsigned short* __restrict__ dst)
{
  const size_t i = ((size_t)blockIdx.x * 256 + threadIdx.x) * 8;
  const float4 a = *(const float4*)&src[i];
  const float4 b = *(const float4*)&src[i + 4];
  union { int4 v; unsigned short u[8]; } o;
  o.u[0] = f2b(a.x); o.u[1] = f2b(a.y); o.u[2] = f2b(a.z); o.u[3] = f2b(a.w);
  o.u[4] = f2b(b.x); o.u[5] = f2b(b.y); o.u[6] = f2b(b.z); o.u[7] = f2b(b.w);
  *(int4*)&dst[i] = o.v;
}

// ---------------- RMSNorm: fp32 in -> bf16 out ----------------
__global__ __launch_bounds__(256)
void rmsnorm_k(const float* __restrict__ X, const float* __restrict__ gamma,
               unsigned short* __restrict__ Y)
{
  const int row = blockIdx.x, t = threadIdx.x;
  const float* xr = X + (size_t)row * DIM;
  float4 v[4];
  float ss = 0.f;
#pragma unroll
  for (int p = 0; p < 4; ++p) {
    v[p] = *(const float4*)&xr[p * 1024 + t * 4];
    ss += v[p].x*v[p].x + v[p].y*v[p].y + v[p].z*v[p].z + v[p].w*v[p].w;
  }
#pragma unroll
  for (int off = 32; off >= 1; off >>= 1) ss += __shfl_xor(ss, off, 64);
  __shared__ float red[4];
  if ((t & 63) == 0) red[t >> 6] = ss;
  __syncthreads();
  const float tot = red[0] + red[1] + red[2] + red[3];
  const float rn = rsqrtf(tot * (1.f / DIM) + 1e-6f);
  unsigned short* yr = Y + (size_t)row * DIM;
#pragma unroll
  for (int p = 0; p < 4; ++p) {
    const float4 gv = *(const float4*)&gamma[p * 1024 + t * 4];
    short4 o;
    o.x = (short)f2b(v[p].x * gv.x * rn);
    o.y = (short)f2b(v[p].y * gv.y * rn);
    o.z = (short)f2b(v[p].z * gv.z * rn);
    o.w = (short)f2b(v[p].w * gv.w * rn);
    *(short4*)&yr[p * 1024 + t * 4] = o;
  }
}

// ---------------- RoPE in-place on bf16 [rows][NHT*128] ----------------
template<int NHT>
__global__ __launch_bounds__(256)
void rope_k(unsigned short* __restrict__ buf, const float* __restrict__ fr)
{
  const int u = blockIdx.x * 256 + threadIdx.x;
  const int per_row = NHT * 16;
  const int row  = u / per_row;
  const int rem  = u - row * per_row;
  const int head = rem >> 4;
  const int i4   = (rem & 15) << 2;
  const int s    = row & (SEQ - 1);
  unsigned short* p = buf + (size_t)row * (NHT * HD) + head * HD + i4 * 2;
  union { int4 v; unsigned short u16[8]; } d;
  d.v = *(const int4*)p;
  const float4 f = *(const float4*)&fr[s * 64 + i4];
  const float fa[4] = {f.x, f.y, f.z, f.w};
#pragma unroll
  for (int i = 0; i < 4; ++i) {
    float sn, c;
    __sincosf(fa[i], &sn, &c);
    const float x0 = b2f(d.u16[2*i]), x1 = b2f(d.u16[2*i+1]);
    d.u16[2*i]   = f2b(x0 * c - x1 * sn);
    d.u16[2*i+1] = f2b(x0 * sn + x1 * c);
  }
  *(int4*)p = d.v;
}

// ======================= 256x256 GEMM, 2 barriers / K=32 phase =======================
// Per phase p: read sigma_p fragments (12 ds_read_b128), stage sigma_{p+3} (4 gll16),
// 32 MFMA (compiler-interleaved counted lgkmcnt), counted vmcnt(8), barrier.
// Ring-of-4 k32 sub-tiles per operand (128 KiB LDS). Work order: XCD-chunk ->
// (tm_group of 8) x (tn) x (tm_in) — A-strip L3-resident, weights ~read-once.
// MODE 0: QKV fused (+bias->bf16); 1: O-proj (+bias+res->f32);
// MODE 2: W2 (+res->f32); 3: W13 fused SwiGLU (->bf16).
template<int MODE>
__global__ __launch_bounds__(512)
void gemm256(const unsigned short* __restrict__ A,
             const unsigned short* __restrict__ W,
             const unsigned short* __restrict__ W3p,
             const float* __restrict__ bias,
             const float* res,
             float* outF,
             unsigned short* __restrict__ outH,
             const unsigned short* __restrict__ wkp,
             const unsigned short* __restrict__ wvp,
             const float* __restrict__ bkp,
             const float* __restrict__ bvp,
             unsigned short* __restrict__ okp,
             unsigned short* __restrict__ ovp,
             int K)
{
  __shared__ __align__(16) char smem[131072];
  const int t = threadIdx.x, lane = t & 63, wid = t >> 6;
  const int wr = wid >> 2, wc = wid & 3;
  const int G = gridDim.x, bid = blockIdx.x;
  const int wg = (bid & 7) * (G >> 3) + (bid >> 3);   // XCD-chunked
  const int NBN = G >> 5;                             // NBM = 32 (M = 8192)
  const int span = NBN << 3;                          // TMG = 8
  const int tmg = wg / span, rr = wg - tmg * span;
  const int tn = rr >> 3, tm = (tmg << 3) + (rr & 7);
  const int m0 = tm << 8;
  const int NSUB = K >> 5;

  const unsigned short *P1, *P2;
  const float* bp = bias;
  unsigned short* oh = outH;
  int nloc = 0, colsN = 4096;
  if constexpr (MODE == 0) {
    const int n0 = tn << 8;
    if (n0 < 4096)      { nloc = n0;        P1 = W   + (size_t)nloc * K; bp = bias; oh = outH; colsN = 4096; }
    else if (n0 < 5120) { nloc = n0 - 4096; P1 = wkp + (size_t)nloc * K; bp = bkp;  oh = okp;  colsN = 1024; }
    else                { nloc = n0 - 5120; P1 = wvp + (size_t)nloc * K; bp = bvp;  oh = ovp;  colsN = 1024; }
    P2 = P1 + (size_t)128 * K;
  } else if constexpr (MODE == 3) {
    const int n0w = tn << 7;
    P1 = W   + (size_t)n0w * K;
    P2 = W3p + (size_t)n0w * K;
    nloc = n0w;
  } else {
    const int n0 = tn << 8;
    P1 = W + (size_t)n0 * K;
    P2 = P1 + (size_t)128 * K;
    nloc = n0;
  }

  const int r0 = t >> 2, gg = t & 3;
  const int gsw = gg ^ ((r0 >> 1) & 3);

  auto stA = [&](int sig) {
    if (sig < NSUB) {
      const int slot = sig & 3;
      gll16(A + (size_t)(m0 + r0) * K + sig * 32 + gsw * 8,
            smem + slot * 16384 + wid * 1024);
      gll16(A + (size_t)(m0 + 128 + r0) * K + sig * 32 + gsw * 8,
            smem + slot * 16384 + 8192 + wid * 1024);
    }
  };
  auto stB = [&](int sig) {
    if (sig < NSUB) {
      const int slot = sig & 3;
      gll16(P1 + (size_t)r0 * K + sig * 32 + gsw * 8,
            smem + 65536 + slot * 16384 + wid * 1024);
      gll16(P2 + (size_t)r0 * K + sig * 32 + gsw * 8,
            smem + 65536 + slot * 16384 + 8192 + wid * 1024);
    }
  };
  auto rdA = [&](int slot, int mo) -> bf16x8_t {
    const int lrow = wr * 128 + mo + (lane & 15);
    const int g = (lane >> 4) ^ ((lrow >> 1) & 3);
    return *(const bf16x8_t*)(smem + slot * 16384 + lrow * 64 + g * 16);
  };
  auto rdB = [&](int slot, int nf) -> bf16x8_t {
    const int brow = wc * 64 + nf * 16 + (lane & 15);
    const int g = (lane >> 4) ^ ((brow >> 1) & 3);
    return *(const bf16x8_t*)(smem + 65536 + slot * 16384 + brow * 64 + g * 16);
  };

  f32x4_t acc[8][4];
#pragma unroll
  for (int i = 0; i < 8; ++i)
#pragma unroll
    for (int j = 0; j < 4; ++j) acc[i][j] = (f32x4_t)0.f;

  stA(0); stB(0); stA(1); stB(1); stA(2); stB(2);
  VM8;
  __builtin_amdgcn_s_barrier();

  for (int p = 0; p < NSUB; ++p) {
    const int slot = p & 3;
    bf16x8_t bfv[4], afv[8];
#pragma unroll
    for (int n = 0; n < 4; ++n) bfv[n] = rdB(slot, n);
#pragma unroll
    for (int m = 0; m < 8; ++m) afv[m] = rdA(slot, m * 16);
    stA(p + 3); stB(p + 3);
    __builtin_amdgcn_s_setprio(1);
#pragma unroll
    for (int m = 0; m < 8; ++m)
#pragma unroll
      for (int n = 0; n < 4; ++n)
        acc[m][n] = __builtin_amdgcn_mfma_f32_16x16x32_bf16(afv[m], bfv[n], acc[m][n], 0, 0, 0);
    __builtin_amdgcn_s_setprio(0);
    if (p < NSUB - 3)      { VM8; }
    else if (p == NSUB - 3){ VM4M; }
    else                   { VM0; }
    __builtin_amdgcn_s_barrier();
  }

  if constexpr (MODE == 0) {
#pragma unroll
    for (int ni = 0; ni < 4; ++ni) {
      const int col = nloc + wc * 64 + ni * 16 + (lane & 15);
      const float bv = bp[col];
#pragma unroll
      for (int mi = 0; mi < 8; ++mi)
#pragma unroll
        for (int r = 0; r < 4; ++r) {
          const int row = m0 + wr * 128 + mi * 16 + (lane >> 4) * 4 + r;
          oh[(size_t)row * colsN + col] = f2b(acc[mi][ni][r] + bv);
        }
    }
  } else if constexpr (MODE == 1 || MODE == 2) {
#pragma unroll
    for (int ni = 0; ni < 4; ++ni) {
      const int col = nloc + wc * 64 + ni * 16 + (lane & 15);
      float bv = 0.f;
      if constexpr (MODE == 1) bv = bias[col];
#pragma unroll
      for (int mi = 0; mi < 8; ++mi)
#pragma unroll
        for (int r = 0; r < 4; ++r) {
          const int row = m0 + wr * 128 + mi * 16 + (lane >> 4) * 4 + r;
          const size_t idx = (size_t)row * 4096 + col;
          outF[idx] = acc[mi][ni][r] + bv + res[idx];
        }
    }
  } else {
    if (wc >= 2) {
      const int widx = wr * 2 + (wc - 2);
#pragma unroll
      for (int ni = 0; ni < 4; ++ni)
#pragma unroll
        for (int mi = 0; mi < 8; ++mi)
#pragma unroll
          for (int r = 0; r < 4; ++r) {
            const int lrow = mi * 16 + (lane >> 4) * 4 + r;
            const int ncol = ni * 16 + (lane & 15);
            *(unsigned short*)(smem + widx * 16384 + lrow * 128 + ncol * 2) =
                f2b(acc[mi][ni][r]);
          }
    }
    __syncthreads();
    if (wc < 2) {
      const int widx = wr * 2 + wc;
#pragma unroll
      for (int ni = 0; ni < 4; ++ni)
#pragma unroll
        for (int mi = 0; mi < 8; ++mi)
#pragma unroll
          for (int r = 0; r < 4; ++r) {
            const int lrow = mi * 16 + (lane >> 4) * 4 + r;
            const int ncol = ni * 16 + (lane & 15);
            const float s3 = b2f(*(const unsigned short*)(smem + widx * 16384 + lrow * 128 + ncol * 2));
            const float s1 = acc[mi][ni][r];
            const float sig = 1.f / (1.f + __expf(-s1));
            const int row = m0 + wr * 128 + lrow;
            outH[(size_t)row * FFNH + nloc + wc * 64 + ncol] = f2b(s1 * sig * s3);
          }
    }
  }
}

// ---------------- Flash attention (non-causal, GQA 4:1) ----------------
// Pair-processed: 2 KV tiles (64 positions) per softmax/barrier round.
// Ring-2 LDS holds the pair; exact defer-max skips the O-rescale when the
// running max doesn't grow (corr would be exactly 1).
__global__ __launch_bounds__(256)
void attn_k(const unsigned short* __restrict__ Q, const unsigned short* __restrict__ Kb,
            const unsigned short* __restrict__ Vb, unsigned short* __restrict__ O)
{
  __shared__ unsigned short Qs[8192];
  __shared__ unsigned short Ks[2][4096];
  __shared__ unsigned short Vt[2][4096];
  __shared__ unsigned short Ps[2][2048];
  const int t = threadIdx.x, lane = t & 63, wid = t >> 6;
  const int bx = blockIdx.x;
  const int qt = bx & 31, h = (bx >> 5) & 31, b = bx >> 10;
  const int kvh = h >> 2;
  const float rs = 0.08838834764831845f;

#pragma unroll
  for (int oo = 0; oo < 4; ++oo) {
    const int o = wid * 4 + oo;
    const int row = o * 4 + (lane >> 4);
    const int gl  = (lane & 15) ^ (row & 7);
    gll16(Q + (size_t)(b * SEQ + qt * 64 + row) * DIM + h * HD + gl * 8, &Qs[o * 512]);
  }

  const unsigned short* Kbase = Kb + (size_t)(b * SEQ) * (NKV * HD) + kvh * HD;
  const unsigned short* Vbase = Vb + (size_t)(b * SEQ) * (NKV * HD) + kvh * HD;

  auto stK = [&](int kt, int slot) {
#pragma unroll
    for (int oo = 0; oo < 2; ++oo) {
      const int o = wid * 2 + oo;
      const int row = o * 4 + (lane >> 4);
      const int gl  = (lane & 15) ^ (row & 7);
      gll16(Kbase + (size_t)(kt * 32 + row) * (NKV * HD) + gl * 8, &Ks[slot][o * 512]);
    }
  };
  const int kv = t >> 3, dc = (t & 7) << 4;
  const int colv = kv ^ ((t & 3) << 3);
  auto ldV = [&](int kt, int4& lo, int4& hi) {
    const unsigned short* gp = Vbase + (size_t)(kt * 32 + kv) * (NKV * HD) + dc;
    lo = *(const int4*)gp;
    hi = *(const int4*)(gp + 8);
  };
  auto wrV = [&](int slot, int4 vlo, int4 vhi) {
    union { int4 v; unsigned short u[8]; } lo, hi;
    lo.v = vlo; hi.v = vhi;
#pragma unroll
    for (int j = 0; j < 8; ++j) Vt[slot][(dc + j) * 32 + colv] = lo.u[j];
#pragma unroll
    for (int j = 0; j < 8; ++j) Vt[slot][(dc + 8 + j) * 32 + colv] = hi.u[j];
  };

  int4 vlo0, vhi0, vlo1, vhi1;
  stK(0, 0); ldV(0, vlo0, vhi0);
  stK(1, 1); ldV(1, vlo1, vhi1);

  f32x4_t oa[8];
#pragma unroll
  for (int i = 0; i < 8; ++i) oa[i] = (f32x4_t)0.f;
  float mrun[4] = {-1e30f, -1e30f, -1e30f, -1e30f};
  float lrun[4] = {0.f, 0.f, 0.f, 0.f};
  const int q0 = wid * 16;

  for (int kp = 0; kp < SEQ / 64; ++kp) {
    VM0;                                   // K pair, V pair (and Q on kp=0) landed
    wrV(0, vlo0, vhi0);
    wrV(1, vlo1, vhi1);
    asm volatile("s_waitcnt lgkmcnt(0)" ::: "memory");
    __builtin_amdgcn_s_barrier();          // pair fully staged, visible to all waves

    // S = Q K^T for both tiles (4 accumulators)
    f32x4_t sa0 = (f32x4_t)0.f, sa1 = (f32x4_t)0.f;
    f32x4_t sa2 = (f32x4_t)0.f, sa3 = (f32x4_t)0.f;
    const int arow = q0 + (lane & 15);
    const int kr0 = lane & 15, kr1 = 16 + (lane & 15);
#pragma unroll
    for (int ks = 0; ks < 4; ++ks) {
      const bf16x8_t aq  = *(const bf16x8_t*)&Qs[(arow * 128 + ks * 32 + (lane >> 4) * 8) ^ ((arow & 7) << 3)];
      const bf16x8_t b00 = *(const bf16x8_t*)&Ks[0][(kr0 * 128 + ks * 32 + (lane >> 4) * 8) ^ ((kr0 & 7) << 3)];
      sa0 = __builtin_amdgcn_mfma_f32_16x16x32_bf16(aq, b00, sa0, 0, 0, 0);
      const bf16x8_t b01 = *(const bf16x8_t*)&Ks[0][(kr1 * 128 + ks * 32 + (lane >> 4) * 8) ^ ((kr1 & 7) << 3)];
      sa1 = __builtin_amdgcn_mfma_f32_16x16x32_bf16(aq, b01, sa1, 0, 0, 0);
      const bf16x8_t b10 = *(const bf16x8_t*)&Ks[1][(kr0 * 128 + ks * 32 + (lane >> 4) * 8) ^ ((kr0 & 7) << 3)];
      sa2 = __builtin_amdgcn_mfma_f32_16x16x32_bf16(aq, b10, sa2, 0, 0, 0);
      const bf16x8_t b11 = *(const bf16x8_t*)&Ks[1][(kr1 * 128 + ks * 32 + (lane >> 4) * 8) ^ ((kr1 & 7) << 3)];
      sa3 = __builtin_amdgcn_mfma_f32_16x16x32_bf16(aq, b11, sa3, 0, 0, 0);
    }

    // one softmax pass over 64 KV positions
    float pm[4];
#pragma unroll
    for (int r = 0; r < 4; ++r) {
      float v = fmaxf(fmaxf(sa0[r], sa1[r]), fmaxf(sa2[r], sa3[r])) * rs;
#pragma unroll
      for (int off = 1; off < 16; off <<= 1) v = fmaxf(v, __shfl_xor(v, off, 64));
      pm[r] = v;
    }
    const int grow = __any(pm[0] > mrun[0] || pm[1] > mrun[1] ||
                           pm[2] > mrun[2] || pm[3] > mrun[3]);
    if (grow) {
#pragma unroll
      for (int r = 0; r < 4; ++r) {
        const float mnew = fmaxf(mrun[r], pm[r]);
        const float corr = __expf(mrun[r] - mnew);
        mrun[r] = mnew;
        lrun[r] *= corr;
#pragma unroll
        for (int i = 0; i < 8; ++i) oa[i][r] *= corr;
      }
    }
    float pv0[4], pv1[4], pv2[4], pv3[4];
#pragma unroll
    for (int r = 0; r < 4; ++r) {
      pv0[r] = __expf(sa0[r] * rs - mrun[r]);
      pv1[r] = __expf(sa1[r] * rs - mrun[r]);
      pv2[r] = __expf(sa2[r] * rs - mrun[r]);
      pv3[r] = __expf(sa3[r] * rs - mrun[r]);
    }
#pragma unroll
    for (int r = 0; r < 4; ++r) {
      float v = pv0[r] + pv1[r] + pv2[r] + pv3[r];
#pragma unroll
      for (int off = 1; off < 16; off <<= 1) v += __shfl_xor(v, off, 64);
      lrun[r] += v;
    }

    // P -> LDS (per-wave region, per-tile halves), re-read as A fragments
#pragma unroll
    for (int r = 0; r < 4; ++r) {
      const int prow = (lane >> 4) * 4 + r;
      Ps[0][wid * 512 + prow * 32 + (lane & 15)]      = f2b(pv0[r]);
      Ps[0][wid * 512 + prow * 32 + 16 + (lane & 15)] = f2b(pv1[r]);
      Ps[1][wid * 512 + prow * 32 + (lane & 15)]      = f2b(pv2[r]);
      Ps[1][wid * 512 + prow * 32 + 16 + (lane & 15)] = f2b(pv3[r]);
    }
    const bf16x8_t pf0 = *(const bf16x8_t*)&Ps[0][wid * 512 + (lane & 15) * 32 + (lane >> 4) * 8];
    const bf16x8_t pf1 = *(const bf16x8_t*)&Ps[1][wid * 512 + (lane & 15) * 32 + (lane >> 4) * 8];

    // O += P V for both tiles
#pragma unroll
    for (int nt2 = 0; nt2 < 8; ++nt2) {
      const bf16x8_t vf0 = *(const bf16x8_t*)&Vt[0][(nt2 * 16 + (lane & 15)) * 32 + (((lane >> 4) ^ (nt2 & 3)) << 3)];
      oa[nt2] = __builtin_amdgcn_mfma_f32_16x16x32_bf16(pf0, vf0, oa[nt2], 0, 0, 0);
      const bf16x8_t vf1 = *(const bf16x8_t*)&Vt[1][(nt2 * 16 + (lane & 15)) * 32 + (((lane >> 4) ^ (nt2 & 3)) << 3)];
      oa[nt2] = __builtin_amdgcn_mfma_f32_16x16x32_bf16(pf1, vf1, oa[nt2], 0, 0, 0);
    }
    __builtin_amdgcn_s_barrier();          // all waves done with this pair
    if (kp + 1 < SEQ / 64) {
      stK(2 * kp + 2, 0); ldV(2 * kp + 2, vlo0, vhi0);
      stK(2 * kp + 3, 1); ldV(2 * kp + 3, vlo1, vhi1);
    }
  }

  float inv[4];
#pragma unroll
  for (int r = 0; r < 4; ++r) inv[r] = 1.f / lrun[r];
#pragma unroll
  for (int nt2 = 0; nt2 < 8; ++nt2) {
    const int col = h * HD + nt2 * 16 + (lane & 15);
#pragma unroll
    for (int r = 0; r < 4; ++r) {
      const int row = qt * 64 + q0 + (lane >> 4) * 4 + r;
      O[(size_t)(b * SEQ + row) * DIM + col] = f2b(oa[nt2][r] * inv[r]);
    }
  }
}

// ---------------- launch ----------------
extern "C" void kernel_launch(void* const* d_in, const int* in_sizes, int n_in,
                              void* d_out, int out_size, void* d_ws, size_t ws_size,
                              hipStream_t stream)
{
  (void)in_sizes; (void)n_in; (void)out_size; (void)ws_size;
  const float* x   = (const float*)d_in[0];
  const float* fr  = (const float*)d_in[1];
  const float* ga  = (const float*)d_in[3];
  const float* gf  = (const float*)d_in[4];
  const float* wq  = (const float*)d_in[5];
  const float* wqb = (const float*)d_in[6];
  const float* wk  = (const float*)d_in[7];
  const float* wkb = (const float*)d_in[8];
  const float* wv  = (const float*)d_in[9];
  const float* wvb = (const float*)d_in[10];
  const float* wo  = (const float*)d_in[11];
  const float* wob = (const float*)d_in[12];
  const float* w1  = (const float*)d_in[13];
  const float* w3  = (const float*)d_in[14];
  const float* w2  = (const float*)d_in[15];
  float* out = (float*)d_out;

  constexpr size_t MB = 1ull << 20;
  char* ws = (char*)d_ws;
  unsigned short* xn = (unsigned short*)(ws);              // [0,64) MiB
  unsigned short* qb = (unsigned short*)(ws + 64*MB);      // [64,128)
  unsigned short* kb = (unsigned short*)(ws + 128*MB);     // [128,144)
  unsigned short* vb = (unsigned short*)(ws + 144*MB);     // [144,160)
  unsigned short* ao = (unsigned short*)(ws + 160*MB);     // [160,224)
  unsigned short* hn = (unsigned short*)(ws + 224*MB);     // [224,288)
  unsigned short* g  = (unsigned short*)(ws);              // [0,172) alias (dead by FFN time)
  unsigned short* wscr = (unsigned short*)(ws + 288*MB);   // JIT bf16 weights
  unsigned short* wqB = wscr;                               // 32 MiB
  unsigned short* wkB = wscr + 16*MB;                       // 8 MiB
  unsigned short* wvB = wscr + 20*MB;                       // 8 MiB
  unsigned short* woB = wscr;                               // 32 MiB (after QKV)
  unsigned short* w1B = wscr;                               // 90 MiB
  unsigned short* w3B = wscr + 45*MB;                       // 90 MiB
  unsigned short* w2B = wscr;                               // 90 MiB

  rmsnorm_k<<<MTOT, 256, 0, stream>>>(x, ga, xn);
  cvt_bf16_k<<<(NH*HD*DIM)/2048,  256, 0, stream>>>(wq, wqB);
  cvt_bf16_k<<<(NKV*HD*DIM)/2048, 256, 0, stream>>>(wk, wkB);
  cvt_bf16_k<<<(NKV*HD*DIM)/2048, 256, 0, stream>>>(wv, wvB);
  gemm256<0><<<(MTOT/256)*((DIM+2*NKV*HD)/256), 512, 0, stream>>>(
      xn, wqB, nullptr, wqb, nullptr, nullptr, qb,
      wkB, wvB, wkb, wvb, kb, vb, DIM);
  rope_k<NH><<<(MTOT*NH*16)/256,  256, 0, stream>>>(qb, fr);
  rope_k<NKV><<<(MTOT*NKV*16)/256,256, 0, stream>>>(kb, fr);
  attn_k<<<BATCH*NH*(SEQ/64), 256, 0, stream>>>(qb, kb, vb, ao);
  cvt_bf16_k<<<(DIM*DIM)/2048, 256, 0, stream>>>(wo, woB);
  gemm256<1><<<(MTOT/256)*(DIM/256), 512, 0, stream>>>(
      ao, woB, nullptr, wob, x, out, nullptr,
      nullptr, nullptr, nullptr, nullptr, nullptr, nullptr, DIM);
  rmsnorm_k<<<MTOT, 256, 0, stream>>>(out, gf, hn);
  cvt_bf16_k<<<(FFNH*DIM)/2048, 256, 0, stream>>>(w1, w1B);
  cvt_bf16_k<<<(FFNH*DIM)/2048, 256, 0, stream>>>(w3, w3B);
  gemm256<3><<<(MTOT/256)*(FFNH/128), 512, 0, stream>>>(
      hn, w1B, w3B, nullptr, nullptr, nullptr, g,
      nullptr, nullptr, nullptr, nullptr, nullptr, nullptr, DIM);
  cvt_bf16_k<<<(FFNH*DIM)/2048, 256, 0, stream>>>(w2, w2B);
  gemm256<2><<<(MTOT/256)*(DIM/256), 512, 0, stream>>>(
      g, w2B, nullptr, nullptr, out, out, nullptr,
      nullptr, nullptr, nullptr, nullptr, nullptr, nullptr, FFNH);
}